// Round 10
// baseline (334.003 us; speedup 1.0000x reference)
//
#include <hip/hip_runtime.h>
#include <hip/hip_fp16.h>
#include <math.h>

#define NBINS   4096
#define GB_HIST 256     // hist blocks (512 threads each)
#define GBC     256     // scatter slabs == scatter grid
#define SUBC    4       // count sub-blocks per slab
#define CAP     2048
#define DCH     64
#define BKT     128     // nodes per bucket
#define NBMAX   512     // max buckets (N <= 65536)
#define SCAN_CH 2048

struct Ctrl {
    double thr;
    int cand_cnt;
    int b0, b1;
    int base0;
    float s0, s1;
};

__device__ __forceinline__ int bin_of(float v) {
    int b = (int)(v * (float)NBINS);
    if (b < 0) b = 0;
    if (b >= NBINS) b = NBINS - 1;
    return b;
}

// ---------- LDS histogram, dense (non-atomic) flush. 256 blocks x 512 ----------
__global__ void k_hist(const float* __restrict__ att, int E, int* __restrict__ hist2d) {
    __shared__ int lh[NBINS];   // 16 KB
    int t = threadIdx.x;
    for (int b = t; b < NBINS; b += 512) lh[b] = 0;
    __syncthreads();
    for (int i = blockIdx.x * 512 + t; i < E; i += GB_HIST * 512)
        atomicAdd(&lh[bin_of(att[i])], 1);
    __syncthreads();
    for (int b = t; b < NBINS; b += 512)
        hist2d[blockIdx.x * NBINS + b] = lh[b];
}

// 64 blocks x 256: each block folds 64 bins; 4 threads per bin sum 64 partials each.
__global__ void k_fold(const int* __restrict__ hist2d, int* __restrict__ hist,
                       int* __restrict__ csum) {
    __shared__ int sh[256];
    int t = threadIdx.x;
    int j = blockIdx.x * 64 + (t & 63);
    int p = t >> 6;   // 0..3
    int s = 0;
    for (int q = 0; q < GB_HIST / 4; q++)
        s += hist2d[(p * (GB_HIST / 4) + q) * NBINS + j];
    sh[t] = s;
    __syncthreads();
    if (p == 0) {
        int h = sh[t] + sh[t + 64] + sh[t + 128] + sh[t + 192];
        hist[j] = h;
        int r = h;
        for (int off = 32; off > 0; off >>= 1) r += __shfl_down(r, off, 64);
        if (t == 0) csum[blockIdx.x] = r;
    }
}

// 1 block x 256: scan 64 chunk-sums, then 64 bins in the hit chunks -> b0, b1, base0
__global__ void k_pick(const int* __restrict__ hist, const int* __restrict__ csum,
                       Ctrl* ctrl, long long i0, long long i1) {
    __shared__ int sh[256];
    __shared__ int c0s, c1s;
    __shared__ long long e0s, e1s;
    int t = threadIdx.x;
    int v = (t < 64) ? csum[t] : 0;
    sh[t] = v;
    __syncthreads();
    for (int off = 1; off < 256; off <<= 1) {
        int u = (t >= off) ? sh[t - off] : 0;
        __syncthreads(); sh[t] += u; __syncthreads();
    }
    long long excl = (long long)(sh[t] - v);
    if (t < 64) {
        if (i0 >= excl && i0 < excl + v) { c0s = t; e0s = excl; }
        if (i1 >= excl && i1 < excl + v) { c1s = t; e1s = excl; }
    }
    __syncthreads();
    int c0 = c0s, c1 = c1s;
    long long e0 = e0s, e1 = e1s;

    int hv = (t < 64) ? hist[c0 * 64 + t] : 0;
    sh[t] = hv; __syncthreads();
    for (int off = 1; off < 256; off <<= 1) {
        int u = (t >= off) ? sh[t - off] : 0;
        __syncthreads(); sh[t] += u; __syncthreads();
    }
    long long be = e0 + (long long)(sh[t] - hv);
    if (t < 64 && i0 >= be && i0 < be + hv) { ctrl->b0 = c0 * 64 + t; ctrl->base0 = (int)be; }
    __syncthreads();

    hv = (t < 64) ? hist[c1 * 64 + t] : 0;
    sh[t] = hv; __syncthreads();
    for (int off = 1; off < 256; off <<= 1) {
        int u = (t >= off) ? sh[t - off] : 0;
        __syncthreads(); sh[t] += u; __syncthreads();
    }
    be = e1 + (long long)(sh[t] - hv);
    if (t < 64 && i1 >= be && i1 < be + hv) { ctrl->b1 = c1 * 64 + t; }
}

// ---------- count + candidate collect: GBC*SUBC blocks x 256 ----------
// bin > b1  -> definitely kept: count per (slab,sub,bucket) for dst and src
// bin in [b0,b1] -> candidate: append (i, v) to global list (~400-800 entries)
__global__ void k_countc(const float* __restrict__ att, const int* __restrict__ src,
                         const int* __restrict__ dst, int E, int NB, int NBG,
                         Ctrl* __restrict__ ctrl, int* __restrict__ cntAll,
                         uint2* __restrict__ cand) {
    __shared__ int lD[NBMAX], lS[NBMAX];
    int t = threadIdx.x;
    for (int b = t; b < NB; b += 256) { lD[b] = 0; lS[b] = 0; }
    __syncthreads();
    int bb = blockIdx.x;
    int k = bb & (GBC - 1);
    int s = bb >> 8;            // GBC = 256
    int b0 = ctrl->b0, b1 = ctrl->b1;
    for (int c = k + GBC * s; c * 1024 < E; c += GBC * SUBC) {
        int base = c * 1024;
        for (int u = t; u < 1024; u += 256) {
            int i = base + u;
            if (i < E) {
                float v = att[i];
                int bin = bin_of(v);
                if (bin > b1) {
                    atomicAdd(&lD[dst[i] >> 7], 1);
                    atomicAdd(&lS[src[i] >> 7], 1);
                } else if (bin >= b0) {
                    int idx = atomicAdd(&ctrl->cand_cnt, 1);
                    if (idx < CAP) {
                        uint2 cv; cv.x = (unsigned)i; cv.y = __float_as_uint(v);
                        cand[idx] = cv;
                    }
                }
            }
        }
    }
    __syncthreads();
    int dbase = (s * GBC + k) * NB;
    for (int b = t; b < NB; b += 256) {
        cntAll[dbase + b]              = lD[b];
        cntAll[SUBC * NBG + dbase + b] = lS[b];
    }
}

// 1 block: exact rank among candidates -> thr (numpy f64 lerp); then add kept
// candidates into cntAll (sub-slot 0) so the scans see exact totals.
__global__ void k_finalize(Ctrl* ctrl, const uint2* __restrict__ cand,
                           const int* __restrict__ src, const int* __restrict__ dst,
                           long long i0, long long i1, double frac,
                           int* __restrict__ cntAll, int NB, int NBG) {
    __shared__ float shv[CAP];
    __shared__ float s0s, s1s;
    __shared__ double thrS;
    int n = ctrl->cand_cnt;
    if (n > CAP) n = CAP;
    int t = threadIdx.x;
    for (int i = t; i < n; i += 256) shv[i] = __uint_as_float(cand[i].y);
    __syncthreads();
    int r0 = (int)(i0 - (long long)ctrl->base0);
    int r1 = (int)(i1 - (long long)ctrl->base0);
    for (int i = t; i < n; i += 256) {
        float v = shv[i];
        int rank = 0;
        for (int j = 0; j < n; j++) {
            float u = shv[j];
            rank += (u < v) || (u == v && j < i);   // stable tie-break => unique ranks
        }
        if (rank == r0) s0s = v;
        if (rank == r1) s1s = v;
    }
    __syncthreads();
    if (t == 0) {
        double a = (double)s0s, b = (double)s1s;
        double thr = b - (b - a) * (1.0 - frac);   // numpy _lerp, t>=0.5 branch
        ctrl->thr = thr; thrS = thr;
        ctrl->s0 = s0s; ctrl->s1 = s1s;
    }
    __syncthreads();
    double thr = thrS;
    for (int i = t; i < n; i += 256) {
        float v = shv[i];
        if ((double)v > thr) {
            int e = (int)cand[i].x;
            int k = (e >> 10) & (GBC - 1);
            atomicAdd(&cntAll[k * NB + (dst[e] >> 7)], 1);
            atomicAdd(&cntAll[SUBC * NBG + k * NB + (src[e] >> 7)], 1);
        }
    }
}

// scan domain j in [0, 2*NBG): (half, bucket=r>>8, blk=r&255); sum SUBC sub-counts
__device__ __forceinline__ int cnt_at(const int* cntAll, int j, int NB, int NBG) {
    int half = (j >= NBG) ? 1 : 0;
    int r = j - half * NBG;
    int b = r >> 8;
    int k = r & (GBC - 1);
    const int* p = cntAll + half * SUBC * NBG + k * NB + b;
    int s = 0;
    #pragma unroll
    for (int q = 0; q < SUBC; q++) s += p[q * GBC * NB];
    return s;
}

__global__ void k_scan1(const int* __restrict__ cntAll, int NB, int NBG, int NK2,
                        int* __restrict__ bsum) {
    __shared__ int sh[8];
    int b = blockIdx.x, t = threadIdx.x;
    int j0 = b * SCAN_CH + t * 8;
    int s = 0;
    for (int u = 0; u < 8; u++) {
        int j = j0 + u;
        if (j < NK2) s += cnt_at(cntAll, j, NB, NBG);
    }
    for (int off = 32; off > 0; off >>= 1) s += __shfl_down(s, off, 64);
    if ((t & 63) == 0) sh[t >> 6] = s;
    __syncthreads();
    if (t == 0) bsum[b] = sh[0] + sh[1] + sh[2] + sh[3];
}

__global__ void k_scan2(const int* __restrict__ bsum, int nb,
                        int* __restrict__ boff, int* __restrict__ off2d, int NK2) {
    __shared__ int sh[256];
    int t = threadIdx.x;
    int v = (t < nb) ? bsum[t] : 0;
    sh[t] = v;
    __syncthreads();
    for (int off = 1; off < 256; off <<= 1) {
        int u = (t >= off) ? sh[t - off] : 0;
        __syncthreads(); sh[t] += u; __syncthreads();
    }
    boff[t] = sh[t] - v;
    if (t == 255) off2d[NK2] = sh[255];
}

__global__ void k_scan3(const int* __restrict__ cntAll, int NB, int NBG, int NK2,
                        const int* __restrict__ boff, int* __restrict__ off2d) {
    __shared__ int sh[256];
    int b = blockIdx.x, t = threadIdx.x;
    int j0 = b * SCAN_CH + t * 8;
    int v[8];
    int ts = 0;
    for (int u = 0; u < 8; u++) {
        int j = j0 + u;
        v[u] = (j < NK2) ? cnt_at(cntAll, j, NB, NBG) : 0;
        ts += v[u];
    }
    sh[t] = ts;
    __syncthreads();
    for (int off = 1; off < 256; off <<= 1) {
        int u = (t >= off) ? sh[t - off] : 0;
        __syncthreads(); sh[t] += u; __syncthreads();
    }
    int excl = boff[b] + sh[t] - ts;
    for (int u = 0; u < 8; u++) {
        int j = j0 + u;
        if (j < NK2) off2d[j] = excl;
        excl += v[u];
    }
}

// ---------- scatter: GBC blocks x 1024 threads; main (bin>b1) + candidate tail ----------
__global__ __launch_bounds__(1024) void k_scatter(
    const float* __restrict__ att, const int* __restrict__ src,
    const int* __restrict__ dst, int E, int NB, int NBG,
    const Ctrl* __restrict__ ctrl, const int* __restrict__ off2d,
    const uint2* __restrict__ cand,
    uint2* __restrict__ ebufD, unsigned* __restrict__ ebufS) {
    __shared__ int baseD[NBMAX], baseS[NBMAX], fD[NBMAX], fS[NBMAX];
    int t = threadIdx.x;
    int K = off2d[NBG];
    for (int b = t; b < NB; b += 1024) {
        baseD[b] = off2d[b * GBC + blockIdx.x];
        baseS[b] = off2d[NBG + b * GBC + blockIdx.x] - K;
        fD[b] = 0; fS[b] = 0;
    }
    __syncthreads();
    int b1 = ctrl->b1;
    for (int i = blockIdx.x * 1024 + t; i < E; i += GBC * 1024) {
        float v = att[i];
        if (bin_of(v) > b1) {
            int s = src[i], d = dst[i];
            int bD = d >> 7, bS = s >> 7;
            int pD = baseD[bD] + atomicAdd(&fD[bD], 1);
            uint2 ev; ev.x = (unsigned)s | ((unsigned)(d & 127) << 16);
            ev.y = __float_as_uint(v);
            ebufD[pD] = ev;
            int pS = baseS[bS] + atomicAdd(&fS[bS], 1);
            unsigned hv = (unsigned)__half_as_ushort(__float2half(v));
            ebufS[pS] = hv | ((unsigned)(s & 127) << 16);
        }
    }
    // candidate tail: place kept candidates belonging to this slab
    double thr = ctrl->thr;
    int nc = ctrl->cand_cnt;
    if (nc > CAP) nc = CAP;
    for (int e = t; e < nc; e += 1024) {
        uint2 cv = cand[e];
        int i = (int)cv.x;
        if (((i >> 10) & (GBC - 1)) != (int)blockIdx.x) continue;
        float v = __uint_as_float(cv.y);
        if ((double)v > thr) {
            int s = src[i], d = dst[i];
            int bD = d >> 7, bS = s >> 7;
            int pD = baseD[bD] + atomicAdd(&fD[bD], 1);
            uint2 ev; ev.x = (unsigned)s | ((unsigned)(d & 127) << 16);
            ev.y = __float_as_uint(v);
            ebufD[pD] = ev;
            int pS = baseS[bS] + atomicAdd(&fS[bS], 1);
            unsigned hv = (unsigned)__half_as_ushort(__float2half(v));
            ebufS[pS] = hv | ((unsigned)(s & 127) << 16);
        }
    }
}

// ---------- fused per-bucket (128 nodes): src-segment sums -> rs, sinv;
//            hx = f16(x*rs); dst-segment counting sort -> packed CSR + rowp ----------
__global__ __launch_bounds__(256) void k_sortsum(
    const int* __restrict__ off2d, int NBG,
    const unsigned* __restrict__ ebufS, const uint2* __restrict__ ebufD,
    const float* __restrict__ x, float* __restrict__ rsums, float* __restrict__ sinv,
    __half* __restrict__ hx,
    unsigned* __restrict__ csr, int* __restrict__ rowp, int N) {
    __shared__ float s128[BKT];
    __shared__ float r128[BKT];
    __shared__ int cnt[BKT], basea[BKT + 1], fill[BKT];
    int b = blockIdx.x, t = threadIdx.x;
    if (t < BKT) { s128[t] = 0.f; cnt[t] = 0; fill[t] = 0; }
    __syncthreads();
    int K = off2d[NBG];
    int slo = off2d[NBG + b * GBC] - K;
    int shi = off2d[NBG + (b + 1) * GBC] - K;
    for (int e = slo + t; e < shi; e += 256) {
        unsigned u = ebufS[e];
        atomicAdd(&s128[(u >> 16) & 127],
                  __half2float(__ushort_as_half((unsigned short)(u & 0xFFFFu))));
    }
    int dlo = off2d[b * GBC], dhi = off2d[(b + 1) * GBC];
    for (int e = dlo + t; e < dhi; e += 256)
        atomicAdd(&cnt[(ebufD[e].x >> 16) & 127], 1);
    __syncthreads();
    if (t < BKT) {
        float sv = (s128[t] > 0.f) ? (s128[t] + 1e-16f) : 1.0f;
        float r = 1.f / sv;
        r128[t] = r;
        int node = b * BKT + t;
        if (node < N) { rsums[node] = r; sinv[node] = sv; }
    }
    if (t == 0) {
        int s = 0;
        for (int i = 0; i < BKT; i++) { basea[i] = s; s += cnt[i]; }
        basea[BKT] = s;
    }
    __syncthreads();
    if (t <= BKT) {
        int node = b * BKT + t;
        if (node <= N) rowp[node] = dlo + basea[t];
    }
    int xbase = b * BKT * DCH;
    for (int i = t; i < BKT * DCH; i += 256) {
        int node = b * BKT + (i >> 6);
        if (node < N) hx[xbase + i] = __float2half(x[xbase + i] * r128[i >> 6]);
    }
    for (int e = dlo + t; e < dhi; e += 256) {
        uint2 ev = ebufD[e];
        int dl = (ev.x >> 16) & 127;
        int pos = dlo + basea[dl] + atomicAdd(&fill[dl], 1);
        unsigned hb = (unsigned)__half_as_ushort(__float2half(__uint_as_float(ev.y)));
        csr[pos] = (ev.x & 0xFFFFu) | (hb << 16);
    }
}

// ---------- spmv: one wave per dst node, packed CSR, f16 state carry ----------
// state recovery: z = h * sinv  (h = f16(z*rs), rs = 1/sinv)
// pass1: hin=hx;  x=hin*si;  z1 = 0.5(az+x);        hout=h1
// pass2: hin=h1;  x=hx*si;   z2 = x + 0.5(az - z1); hout=h2
// pass3: hin=h2;  x=hx*si;   z3 = x + (az - z2);    hout=h3
// pass4: hin=h3;  out = (az + 2*z1 + 4*z2 + z3 - 2x)/6  (z1=ha*si, z2=hb*si, z3=hin*si, x f32)
__global__ __launch_bounds__(256) void k_spmv(
    const int* __restrict__ rowp, const unsigned* __restrict__ csr,
    const __half* __restrict__ hin, __half* __restrict__ hout,
    const __half* __restrict__ hxb, const __half* __restrict__ ha,
    const __half* __restrict__ hb,
    const float* __restrict__ rsums, const float* __restrict__ sinv,
    const float* __restrict__ x, float* __restrict__ zout,
    int N, int pass)
{
    int node = blockIdx.x * 4 + threadIdx.y;
    if (node >= N) return;
    int lane = threadIdx.x;
    int beg = rowp[node], end = rowp[node + 1];

    float a0 = 0.f, a1 = 0.f, a2 = 0.f, a3 = 0.f;
    float a4 = 0.f, a5 = 0.f, a6 = 0.f, a7 = 0.f;
    for (int e = beg; e < end; e += 64) {
        int m = end - e;
        if (m > 64) m = 64;
        unsigned ev = 0;
        if (lane < m) ev = __builtin_nontemporal_load(&csr[e + lane]);   // read-once: keep out of L2
        int j = 0;
        for (; j + 8 <= m; j += 8) {
            unsigned e0 = (unsigned)__shfl((int)ev, j,     64);
            unsigned e1 = (unsigned)__shfl((int)ev, j + 1, 64);
            unsigned e2 = (unsigned)__shfl((int)ev, j + 2, 64);
            unsigned e3 = (unsigned)__shfl((int)ev, j + 3, 64);
            unsigned e4 = (unsigned)__shfl((int)ev, j + 4, 64);
            unsigned e5 = (unsigned)__shfl((int)ev, j + 5, 64);
            unsigned e6 = (unsigned)__shfl((int)ev, j + 6, 64);
            unsigned e7 = (unsigned)__shfl((int)ev, j + 7, 64);
            float z0 = __half2float(hin[(e0 & 0xFFFFu) * DCH + lane]);
            float z1 = __half2float(hin[(e1 & 0xFFFFu) * DCH + lane]);
            float z2 = __half2float(hin[(e2 & 0xFFFFu) * DCH + lane]);
            float z3 = __half2float(hin[(e3 & 0xFFFFu) * DCH + lane]);
            float z4 = __half2float(hin[(e4 & 0xFFFFu) * DCH + lane]);
            float z5 = __half2float(hin[(e5 & 0xFFFFu) * DCH + lane]);
            float z6 = __half2float(hin[(e6 & 0xFFFFu) * DCH + lane]);
            float z7 = __half2float(hin[(e7 & 0xFFFFu) * DCH + lane]);
            a0 = fmaf(__half2float(__ushort_as_half((unsigned short)(e0 >> 16))), z0, a0);
            a1 = fmaf(__half2float(__ushort_as_half((unsigned short)(e1 >> 16))), z1, a1);
            a2 = fmaf(__half2float(__ushort_as_half((unsigned short)(e2 >> 16))), z2, a2);
            a3 = fmaf(__half2float(__ushort_as_half((unsigned short)(e3 >> 16))), z3, a3);
            a4 = fmaf(__half2float(__ushort_as_half((unsigned short)(e4 >> 16))), z4, a4);
            a5 = fmaf(__half2float(__ushort_as_half((unsigned short)(e5 >> 16))), z5, a5);
            a6 = fmaf(__half2float(__ushort_as_half((unsigned short)(e6 >> 16))), z6, a6);
            a7 = fmaf(__half2float(__ushort_as_half((unsigned short)(e7 >> 16))), z7, a7);
        }
        for (; j < m; j++) {
            unsigned e0 = (unsigned)__shfl((int)ev, j, 64);
            float z0 = __half2float(hin[(e0 & 0xFFFFu) * DCH + lane]);
            a0 = fmaf(__half2float(__ushort_as_half((unsigned short)(e0 >> 16))), z0, a0);
        }
    }
    float az = ((a0 + a1) + (a2 + a3)) + ((a4 + a5) + (a6 + a7));

    int idx = node * DCH + lane;
    float si = sinv[node];
    if (pass == 1) {
        float xv = __half2float(hin[idx]) * si;
        float zo = 0.5f * (az + xv);
        hout[idx] = __float2half(zo * rsums[node]);
    } else if (pass == 2) {
        float xv = __half2float(hxb[idx]) * si;
        float z1v = __half2float(hin[idx]) * si;
        float zo = xv + 0.5f * (az - z1v);
        hout[idx] = __float2half(zo * rsums[node]);
    } else if (pass == 3) {
        float xv = __half2float(hxb[idx]) * si;
        float z2v = __half2float(hin[idx]) * si;
        float zo = xv + (az - z2v);
        hout[idx] = __float2half(zo * rsums[node]);
    } else {
        float z1v = __half2float(ha[idx]) * si;
        float z2v = __half2float(hb[idx]) * si;
        float z3v = __half2float(hin[idx]) * si;
        float xv  = __builtin_nontemporal_load(&x[idx]);
        float r   = (az + 2.f * z1v + 4.f * z2v + z3v - 2.f * xv) * (1.0f / 6.0f);
        __builtin_nontemporal_store(r, &zout[idx]);
    }
}

extern "C" void kernel_launch(void* const* d_in, const int* in_sizes, int n_in,
                              void* d_out, int out_size, void* d_ws, size_t ws_size,
                              hipStream_t stream) {
    const float* x   = (const float*)d_in[0];
    const float* att = (const float*)d_in[1];
    const int*   ei  = (const int*)d_in[2];
    const int E = in_sizes[1];
    const int N = in_sizes[0] / DCH;     // NOTE: src packed in 16 bits -> requires N <= 65536
    const int* src = ei;
    const int* dst = ei + E;

    const int NB  = (N + BKT - 1) / BKT;   // 391
    const int NBG = NB * GBC;
    const int NK2 = 2 * NBG;
    const int EK = E - (int)((long long)(0.2 * (double)(E - 1))) + 64;

    char* ws = (char*)d_ws;
    size_t off = 0;
    auto alloc = [&](size_t b) { size_t o = off; off += (b + 255) & ~(size_t)255; return o; };
    int*    hist2d = (int*)   (ws + alloc((size_t)GB_HIST * NBINS * 4));
    int*    hist   = (int*)   (ws + alloc((size_t)NBINS * 4));
    int*    csum   = (int*)   (ws + alloc(64 * 4));
    Ctrl*   ctrl   = (Ctrl*)  (ws + alloc(256));
    uint2*  cand   = (uint2*) (ws + alloc((size_t)CAP * 8));
    int*    cntAll = (int*)   (ws + alloc((size_t)2 * SUBC * NBG * 4));
    int*    off2d  = (int*)   (ws + alloc(((size_t)NK2 + 1) * 4));
    int*    bsum   = (int*)   (ws + alloc(256 * 4));
    int*    boff   = (int*)   (ws + alloc(256 * 4));
    float*  rsums  = (float*) (ws + alloc((size_t)N * 4));
    float*  sinv   = (float*) (ws + alloc((size_t)N * 4));
    int*    rowp   = (int*)   (ws + alloc(((size_t)N + 1) * 4));
    uint2*  ebufD  = (uint2*) (ws + alloc((size_t)EK * 8));
    unsigned* csr32= (unsigned*)(ws + alloc((size_t)EK * 4));
    unsigned* ebufS= (unsigned*)(ws + alloc((size_t)EK * 4));
    __half* hx     = (__half*)(ws + alloc((size_t)N * DCH * 2));
    __half* h1     = (__half*)(ws + alloc((size_t)N * DCH * 2));
    __half* h2     = (__half*)(ws + alloc((size_t)N * DCH * 2));
    __half* h3     = (__half*)(ws + alloc((size_t)N * DCH * 2));
    float*  out    = (float*)d_out;

    hipMemsetAsync(ctrl, 0, 256, stream);

    // numpy-style quantile index arithmetic (float64)
    double q   = 1.0 - 0.8;
    double pos = q * (double)(E - 1);
    long long i0 = (long long)floor(pos);
    double frac  = pos - (double)i0;
    long long i1 = i0 + 1;
    if (i1 > (long long)E - 1) i1 = (long long)E - 1;

    const int nbscan = (NK2 + SCAN_CH - 1) / SCAN_CH;

    k_hist    <<<GB_HIST, 512, 0, stream>>>(att, E, hist2d);
    k_fold    <<<NBINS / 64, 256, 0, stream>>>(hist2d, hist, csum);
    k_pick    <<<1, 256, 0, stream>>>(hist, csum, ctrl, i0, i1);
    k_countc  <<<GBC * SUBC, 256, 0, stream>>>(att, src, dst, E, NB, NBG, ctrl,
                                               cntAll, cand);
    k_finalize<<<1, 256, 0, stream>>>(ctrl, cand, src, dst, i0, i1, frac,
                                      cntAll, NB, NBG);
    k_scan1   <<<nbscan, 256, 0, stream>>>(cntAll, NB, NBG, NK2, bsum);
    k_scan2   <<<1, 256, 0, stream>>>(bsum, nbscan, boff, off2d, NK2);
    k_scan3   <<<nbscan, 256, 0, stream>>>(cntAll, NB, NBG, NK2, boff, off2d);
    k_scatter <<<GBC, 1024, 0, stream>>>(att, src, dst, E, NB, NBG, ctrl, off2d,
                                         cand, ebufD, ebufS);
    k_sortsum <<<NB, 256, 0, stream>>>(off2d, NBG, ebufS, ebufD, x, rsums, sinv, hx,
                                       csr32, rowp, N);

    dim3 blk(64, 4);
    int nb = (N + 3) / 4;
    k_spmv<<<nb, blk, 0, stream>>>(rowp, csr32, hx, h1, hx, nullptr, nullptr, rsums, sinv, x, nullptr, N, 1);
    k_spmv<<<nb, blk, 0, stream>>>(rowp, csr32, h1, h2, hx, nullptr, nullptr, rsums, sinv, x, nullptr, N, 2);
    k_spmv<<<nb, blk, 0, stream>>>(rowp, csr32, h2, h3, hx, nullptr, nullptr, rsums, sinv, x, nullptr, N, 3);
    k_spmv<<<nb, blk, 0, stream>>>(rowp, csr32, h3, nullptr, hx, h1, h2, rsums, sinv, x, out, N, 4);
}

// Round 12
// 323.161 us; speedup vs baseline: 1.0335x; 1.0335x over previous
//
#include <hip/hip_runtime.h>
#include <hip/hip_fp16.h>
#include <math.h>

#define NBINS   4096
#define GB_HIST 256     // hist blocks (512 threads each)
#define GBC     256     // scatter slabs == scatter grid
#define SUBC    4       // count sub-blocks per slab
#define CAP     2048
#define DCH     64
#define BKT     128     // nodes per bucket
#define NBMAX   512     // max buckets (N <= 65536)
#define SCAN_CH 2048

struct Ctrl {
    double thr;
    int cand_cnt;
    int b0, b1;
    int base0;
    float s0, s1;
};

__device__ __forceinline__ int bin_of(float v) {
    int b = (int)(v * (float)NBINS);
    if (b < 0) b = 0;
    if (b >= NBINS) b = NBINS - 1;
    return b;
}

union U32H2 { unsigned u; __half2 h; };

__device__ __forceinline__ float2 h2_to_f2(unsigned u) {
    U32H2 c; c.u = u;
    return __half22float2(c.h);
}
__device__ __forceinline__ unsigned f2_to_h2(float a, float b) {
    U32H2 c; c.h = __floats2half2_rn(a, b);
    return c.u;
}
__device__ __forceinline__ float wt_of(unsigned ev) {
    return __half2float(__ushort_as_half((unsigned short)(ev >> 16)));
}

// ---------- LDS histogram, dense (non-atomic) flush. 256 blocks x 512 ----------
__global__ void k_hist(const float* __restrict__ att, int E, int* __restrict__ hist2d) {
    __shared__ int lh[NBINS];   // 16 KB
    int t = threadIdx.x;
    for (int b = t; b < NBINS; b += 512) lh[b] = 0;
    __syncthreads();
    for (int i = blockIdx.x * 512 + t; i < E; i += GB_HIST * 512)
        atomicAdd(&lh[bin_of(att[i])], 1);
    __syncthreads();
    for (int b = t; b < NBINS; b += 512)
        hist2d[blockIdx.x * NBINS + b] = lh[b];
}

// 64 blocks x 256: each block folds 64 bins; 4 threads per bin sum 64 partials each.
__global__ void k_fold(const int* __restrict__ hist2d, int* __restrict__ hist,
                       int* __restrict__ csum) {
    __shared__ int sh[256];
    int t = threadIdx.x;
    int j = blockIdx.x * 64 + (t & 63);
    int p = t >> 6;   // 0..3
    int s = 0;
    for (int q = 0; q < GB_HIST / 4; q++)
        s += hist2d[(p * (GB_HIST / 4) + q) * NBINS + j];
    sh[t] = s;
    __syncthreads();
    if (p == 0) {
        int h = sh[t] + sh[t + 64] + sh[t + 128] + sh[t + 192];
        hist[j] = h;
        int r = h;
        for (int off = 32; off > 0; off >>= 1) r += __shfl_down(r, off, 64);
        if (t == 0) csum[blockIdx.x] = r;
    }
}

// 1 block x 256: scan 64 chunk-sums, then 64 bins in the hit chunks -> b0, b1, base0
__global__ void k_pick(const int* __restrict__ hist, const int* __restrict__ csum,
                       Ctrl* ctrl, long long i0, long long i1) {
    __shared__ int sh[256];
    __shared__ int c0s, c1s;
    __shared__ long long e0s, e1s;
    int t = threadIdx.x;
    int v = (t < 64) ? csum[t] : 0;
    sh[t] = v;
    __syncthreads();
    for (int off = 1; off < 256; off <<= 1) {
        int u = (t >= off) ? sh[t - off] : 0;
        __syncthreads(); sh[t] += u; __syncthreads();
    }
    long long excl = (long long)(sh[t] - v);
    if (t < 64) {
        if (i0 >= excl && i0 < excl + v) { c0s = t; e0s = excl; }
        if (i1 >= excl && i1 < excl + v) { c1s = t; e1s = excl; }
    }
    __syncthreads();
    int c0 = c0s, c1 = c1s;
    long long e0 = e0s, e1 = e1s;

    int hv = (t < 64) ? hist[c0 * 64 + t] : 0;
    sh[t] = hv; __syncthreads();
    for (int off = 1; off < 256; off <<= 1) {
        int u = (t >= off) ? sh[t - off] : 0;
        __syncthreads(); sh[t] += u; __syncthreads();
    }
    long long be = e0 + (long long)(sh[t] - hv);
    if (t < 64 && i0 >= be && i0 < be + hv) { ctrl->b0 = c0 * 64 + t; ctrl->base0 = (int)be; }
    __syncthreads();

    hv = (t < 64) ? hist[c1 * 64 + t] : 0;
    sh[t] = hv; __syncthreads();
    for (int off = 1; off < 256; off <<= 1) {
        int u = (t >= off) ? sh[t - off] : 0;
        __syncthreads(); sh[t] += u; __syncthreads();
    }
    be = e1 + (long long)(sh[t] - hv);
    if (t < 64 && i1 >= be && i1 < be + hv) { ctrl->b1 = c1 * 64 + t; }
}

// ---------- count + candidate collect: GBC*SUBC blocks x 256 ----------
__global__ void k_countc(const float* __restrict__ att, const int* __restrict__ src,
                         const int* __restrict__ dst, int E, int NB, int NBG,
                         Ctrl* __restrict__ ctrl, int* __restrict__ cntAll,
                         uint2* __restrict__ cand) {
    __shared__ int lD[NBMAX], lS[NBMAX];
    int t = threadIdx.x;
    for (int b = t; b < NB; b += 256) { lD[b] = 0; lS[b] = 0; }
    __syncthreads();
    int bb = blockIdx.x;
    int k = bb & (GBC - 1);
    int s = bb >> 8;            // GBC = 256
    int b0 = ctrl->b0, b1 = ctrl->b1;
    for (int c = k + GBC * s; c * 1024 < E; c += GBC * SUBC) {
        int base = c * 1024;
        for (int u = t; u < 1024; u += 256) {
            int i = base + u;
            if (i < E) {
                float v = att[i];
                int bin = bin_of(v);
                if (bin > b1) {
                    atomicAdd(&lD[dst[i] >> 7], 1);
                    atomicAdd(&lS[src[i] >> 7], 1);
                } else if (bin >= b0) {
                    int idx = atomicAdd(&ctrl->cand_cnt, 1);
                    if (idx < CAP) {
                        uint2 cv; cv.x = (unsigned)i; cv.y = __float_as_uint(v);
                        cand[idx] = cv;
                    }
                }
            }
        }
    }
    __syncthreads();
    int dbase = (s * GBC + k) * NB;
    for (int b = t; b < NB; b += 256) {
        cntAll[dbase + b]              = lD[b];
        cntAll[SUBC * NBG + dbase + b] = lS[b];
    }
}

// 1 block: exact rank among candidates -> thr (numpy f64 lerp); then add kept
// candidates into cntAll (sub-slot 0) so the scans see exact totals.
__global__ void k_finalize(Ctrl* ctrl, const uint2* __restrict__ cand,
                           const int* __restrict__ src, const int* __restrict__ dst,
                           long long i0, long long i1, double frac,
                           int* __restrict__ cntAll, int NB, int NBG) {
    __shared__ float shv[CAP];
    __shared__ float s0s, s1s;
    __shared__ double thrS;
    int n = ctrl->cand_cnt;
    if (n > CAP) n = CAP;
    int t = threadIdx.x;
    for (int i = t; i < n; i += 256) shv[i] = __uint_as_float(cand[i].y);
    __syncthreads();
    int r0 = (int)(i0 - (long long)ctrl->base0);
    int r1 = (int)(i1 - (long long)ctrl->base0);
    for (int i = t; i < n; i += 256) {
        float v = shv[i];
        int rank = 0;
        for (int j = 0; j < n; j++) {
            float u = shv[j];
            rank += (u < v) || (u == v && j < i);   // stable tie-break => unique ranks
        }
        if (rank == r0) s0s = v;
        if (rank == r1) s1s = v;
    }
    __syncthreads();
    if (t == 0) {
        double a = (double)s0s, b = (double)s1s;
        double thr = b - (b - a) * (1.0 - frac);   // numpy _lerp, t>=0.5 branch
        ctrl->thr = thr; thrS = thr;
        ctrl->s0 = s0s; ctrl->s1 = s1s;
    }
    __syncthreads();
    double thr = thrS;
    for (int i = t; i < n; i += 256) {
        float v = shv[i];
        if ((double)v > thr) {
            int e = (int)cand[i].x;
            int k = (e >> 10) & (GBC - 1);
            atomicAdd(&cntAll[k * NB + (dst[e] >> 7)], 1);
            atomicAdd(&cntAll[SUBC * NBG + k * NB + (src[e] >> 7)], 1);
        }
    }
}

// scan domain j in [0, 2*NBG): (half, bucket=r>>8, blk=r&255); sum SUBC sub-counts
__device__ __forceinline__ int cnt_at(const int* cntAll, int j, int NB, int NBG) {
    int half = (j >= NBG) ? 1 : 0;
    int r = j - half * NBG;
    int b = r >> 8;
    int k = r & (GBC - 1);
    const int* p = cntAll + half * SUBC * NBG + k * NB + b;
    int s = 0;
    #pragma unroll
    for (int q = 0; q < SUBC; q++) s += p[q * GBC * NB];
    return s;
}

__global__ void k_scan1(const int* __restrict__ cntAll, int NB, int NBG, int NK2,
                        int* __restrict__ bsum) {
    __shared__ int sh[8];
    int b = blockIdx.x, t = threadIdx.x;
    int j0 = b * SCAN_CH + t * 8;
    int s = 0;
    for (int u = 0; u < 8; u++) {
        int j = j0 + u;
        if (j < NK2) s += cnt_at(cntAll, j, NB, NBG);
    }
    for (int off = 32; off > 0; off >>= 1) s += __shfl_down(s, off, 64);
    if ((t & 63) == 0) sh[t >> 6] = s;
    __syncthreads();
    if (t == 0) bsum[b] = sh[0] + sh[1] + sh[2] + sh[3];
}

__global__ void k_scan2(const int* __restrict__ bsum, int nb,
                        int* __restrict__ boff, int* __restrict__ off2d, int NK2) {
    __shared__ int sh[256];
    int t = threadIdx.x;
    int v = (t < nb) ? bsum[t] : 0;
    sh[t] = v;
    __syncthreads();
    for (int off = 1; off < 256; off <<= 1) {
        int u = (t >= off) ? sh[t - off] : 0;
        __syncthreads(); sh[t] += u; __syncthreads();
    }
    boff[t] = sh[t] - v;
    if (t == 255) off2d[NK2] = sh[255];
}

__global__ void k_scan3(const int* __restrict__ cntAll, int NB, int NBG, int NK2,
                        const int* __restrict__ boff, int* __restrict__ off2d) {
    __shared__ int sh[256];
    int b = blockIdx.x, t = threadIdx.x;
    int j0 = b * SCAN_CH + t * 8;
    int v[8];
    int ts = 0;
    for (int u = 0; u < 8; u++) {
        int j = j0 + u;
        v[u] = (j < NK2) ? cnt_at(cntAll, j, NB, NBG) : 0;
        ts += v[u];
    }
    sh[t] = ts;
    __syncthreads();
    for (int off = 1; off < 256; off <<= 1) {
        int u = (t >= off) ? sh[t - off] : 0;
        __syncthreads(); sh[t] += u; __syncthreads();
    }
    int excl = boff[b] + sh[t] - ts;
    for (int u = 0; u < 8; u++) {
        int j = j0 + u;
        if (j < NK2) off2d[j] = excl;
        excl += v[u];
    }
}

// ---------- scatter: GBC blocks x 1024 threads; main (bin>b1) + candidate tail ----------
__global__ __launch_bounds__(1024) void k_scatter(
    const float* __restrict__ att, const int* __restrict__ src,
    const int* __restrict__ dst, int E, int NB, int NBG,
    const Ctrl* __restrict__ ctrl, const int* __restrict__ off2d,
    const uint2* __restrict__ cand,
    uint2* __restrict__ ebufD, unsigned* __restrict__ ebufS) {
    __shared__ int baseD[NBMAX], baseS[NBMAX], fD[NBMAX], fS[NBMAX];
    int t = threadIdx.x;
    int K = off2d[NBG];
    for (int b = t; b < NB; b += 1024) {
        baseD[b] = off2d[b * GBC + blockIdx.x];
        baseS[b] = off2d[NBG + b * GBC + blockIdx.x] - K;
        fD[b] = 0; fS[b] = 0;
    }
    __syncthreads();
    int b1 = ctrl->b1;
    for (int i = blockIdx.x * 1024 + t; i < E; i += GBC * 1024) {
        float v = att[i];
        if (bin_of(v) > b1) {
            int s = src[i], d = dst[i];
            int bD = d >> 7, bS = s >> 7;
            int pD = baseD[bD] + atomicAdd(&fD[bD], 1);
            uint2 ev; ev.x = (unsigned)s | ((unsigned)(d & 127) << 16);
            ev.y = __float_as_uint(v);
            ebufD[pD] = ev;
            int pS = baseS[bS] + atomicAdd(&fS[bS], 1);
            unsigned hv = (unsigned)__half_as_ushort(__float2half(v));
            ebufS[pS] = hv | ((unsigned)(s & 127) << 16);
        }
    }
    // candidate tail: place kept candidates belonging to this slab
    double thr = ctrl->thr;
    int nc = ctrl->cand_cnt;
    if (nc > CAP) nc = CAP;
    for (int e = t; e < nc; e += 1024) {
        uint2 cv = cand[e];
        int i = (int)cv.x;
        if (((i >> 10) & (GBC - 1)) != (int)blockIdx.x) continue;
        float v = __uint_as_float(cv.y);
        if ((double)v > thr) {
            int s = src[i], d = dst[i];
            int bD = d >> 7, bS = s >> 7;
            int pD = baseD[bD] + atomicAdd(&fD[bD], 1);
            uint2 ev; ev.x = (unsigned)s | ((unsigned)(d & 127) << 16);
            ev.y = __float_as_uint(v);
            ebufD[pD] = ev;
            int pS = baseS[bS] + atomicAdd(&fS[bS], 1);
            unsigned hv = (unsigned)__half_as_ushort(__float2half(v));
            ebufS[pS] = hv | ((unsigned)(s & 127) << 16);
        }
    }
}

// ---------- fused per-bucket (128 nodes): src-segment sums -> rs, sinv;
//            hx = f16(x*rs); dst-segment counting sort -> packed CSR + rowp ----------
__global__ __launch_bounds__(256) void k_sortsum(
    const int* __restrict__ off2d, int NBG,
    const unsigned* __restrict__ ebufS, const uint2* __restrict__ ebufD,
    const float* __restrict__ x, float* __restrict__ rsums, float* __restrict__ sinv,
    __half* __restrict__ hx,
    unsigned* __restrict__ csr, int* __restrict__ rowp, int N) {
    __shared__ float s128[BKT];
    __shared__ float r128[BKT];
    __shared__ int cnt[BKT], basea[BKT + 1], fill[BKT];
    int b = blockIdx.x, t = threadIdx.x;
    if (t < BKT) { s128[t] = 0.f; cnt[t] = 0; fill[t] = 0; }
    __syncthreads();
    int K = off2d[NBG];
    int slo = off2d[NBG + b * GBC] - K;
    int shi = off2d[NBG + (b + 1) * GBC] - K;
    for (int e = slo + t; e < shi; e += 256) {
        unsigned u = ebufS[e];
        atomicAdd(&s128[(u >> 16) & 127],
                  __half2float(__ushort_as_half((unsigned short)(u & 0xFFFFu))));
    }
    int dlo = off2d[b * GBC], dhi = off2d[(b + 1) * GBC];
    for (int e = dlo + t; e < dhi; e += 256)
        atomicAdd(&cnt[(ebufD[e].x >> 16) & 127], 1);
    __syncthreads();
    if (t < BKT) {
        float sv = (s128[t] > 0.f) ? (s128[t] + 1e-16f) : 1.0f;
        float r = 1.f / sv;
        r128[t] = r;
        int node = b * BKT + t;
        if (node < N) { rsums[node] = r; sinv[node] = sv; }
    }
    if (t == 0) {
        int s = 0;
        for (int i = 0; i < BKT; i++) { basea[i] = s; s += cnt[i]; }
        basea[BKT] = s;
    }
    __syncthreads();
    if (t <= BKT) {
        int node = b * BKT + t;
        if (node <= N) rowp[node] = dlo + basea[t];
    }
    int xbase = b * BKT * DCH;
    for (int i = t; i < BKT * DCH; i += 256) {
        int node = b * BKT + (i >> 6);
        if (node < N) hx[xbase + i] = __float2half(x[xbase + i] * r128[i >> 6]);
    }
    for (int e = dlo + t; e < dhi; e += 256) {
        uint2 ev = ebufD[e];
        int dl = (ev.x >> 16) & 127;
        int pos = dlo + basea[dl] + atomicAdd(&fill[dl], 1);
        unsigned hb = (unsigned)__half_as_ushort(__float2half(__uint_as_float(ev.y)));
        csr[pos] = (ev.x & 0xFFFFu) | (hb << 16);
    }
}

// ---------- spmv: one wave per dst node, packed f16x2 gather, half-wave edge pairing ----
// lane = (half h = lane>>5, channel pair c = lane&31). Step j handles edges j+0 (h=0)
// and j+1 (h=1); one uint load fetches channels {2c, 2c+1}. Cross-half shfl_xor(32)
// reduction; 32-lane epilogue on f16x2 words.
// state recovery: z = h * sinv  (h = f16(z*rs), rs = 1/sinv)
__global__ __launch_bounds__(256) void k_spmv(
    const int* __restrict__ rowp, const unsigned* __restrict__ csr,
    const unsigned* __restrict__ hin, unsigned* __restrict__ hout,
    const unsigned* __restrict__ hxb, const unsigned* __restrict__ ha,
    const unsigned* __restrict__ hb,
    const float* __restrict__ rsums, const float* __restrict__ sinv,
    const float* __restrict__ x, float* __restrict__ zout,
    int N, int pass)
{
    int node = blockIdx.x * 4 + threadIdx.y;
    if (node >= N) return;
    int lane = threadIdx.x;
    int h = lane >> 5;        // which edge of the pair
    int c = lane & 31;        // channel pair index
    int beg = rowp[node], end = rowp[node + 1];

    float lo0 = 0.f, lo1 = 0.f, lo2 = 0.f, lo3 = 0.f;
    float hi0 = 0.f, hi1 = 0.f, hi2 = 0.f, hi3 = 0.f;
    for (int e = beg; e < end; e += 64) {
        int m = end - e;
        if (m > 64) m = 64;
        unsigned ev = 0;
        if (lane < m) ev = __builtin_nontemporal_load(&csr[e + lane]);
        for (int j = 0; j < m; j += 8) {
            int s0 = j + h,     s1 = j + 2 + h,  s2 = j + 4 + h,  s3 = j + 6 + h;
            unsigned v0 = (unsigned)__shfl((int)ev, s0 < 64 ? s0 : 63, 64);
            unsigned v1 = (unsigned)__shfl((int)ev, s1 < 64 ? s1 : 63, 64);
            unsigned v2 = (unsigned)__shfl((int)ev, s2 < 64 ? s2 : 63, 64);
            unsigned v3 = (unsigned)__shfl((int)ev, s3 < 64 ? s3 : 63, 64);
            unsigned z0 = (s0 < m) ? hin[(v0 & 0xFFFFu) * 32 + c] : 0u;
            unsigned z1 = (s1 < m) ? hin[(v1 & 0xFFFFu) * 32 + c] : 0u;
            unsigned z2 = (s2 < m) ? hin[(v2 & 0xFFFFu) * 32 + c] : 0u;
            unsigned z3 = (s3 < m) ? hin[(v3 & 0xFFFFu) * 32 + c] : 0u;
            float w0 = (s0 < m) ? wt_of(v0) : 0.f;
            float w1 = (s1 < m) ? wt_of(v1) : 0.f;
            float w2 = (s2 < m) ? wt_of(v2) : 0.f;
            float w3 = (s3 < m) ? wt_of(v3) : 0.f;
            float2 f0 = h2_to_f2(z0); lo0 = fmaf(w0, f0.x, lo0); hi0 = fmaf(w0, f0.y, hi0);
            float2 f1 = h2_to_f2(z1); lo1 = fmaf(w1, f1.x, lo1); hi1 = fmaf(w1, f1.y, hi1);
            float2 f2 = h2_to_f2(z2); lo2 = fmaf(w2, f2.x, lo2); hi2 = fmaf(w2, f2.y, hi2);
            float2 f3 = h2_to_f2(z3); lo3 = fmaf(w3, f3.x, lo3); hi3 = fmaf(w3, f3.y, hi3);
        }
    }
    float alo = (lo0 + lo1) + (lo2 + lo3);
    float ahi = (hi0 + hi1) + (hi2 + hi3);
    alo += __shfl_xor(alo, 32, 64);
    ahi += __shfl_xor(ahi, 32, 64);

    if (h == 0) {
        int idx2 = node * 32 + c;
        float si = sinv[node];
        if (pass == 1) {
            float2 xv = h2_to_f2(hin[idx2]);
            float zlo = 0.5f * (alo + xv.x * si);
            float zhi = 0.5f * (ahi + xv.y * si);
            float rs = rsums[node];
            hout[idx2] = f2_to_h2(zlo * rs, zhi * rs);
        } else if (pass == 2) {
            float2 xv = h2_to_f2(hxb[idx2]);
            float2 zp = h2_to_f2(hin[idx2]);
            float zlo = xv.x * si + 0.5f * (alo - zp.x * si);
            float zhi = xv.y * si + 0.5f * (ahi - zp.y * si);
            float rs = rsums[node];
            hout[idx2] = f2_to_h2(zlo * rs, zhi * rs);
        } else if (pass == 3) {
            float2 xv = h2_to_f2(hxb[idx2]);
            float2 zp = h2_to_f2(hin[idx2]);
            float zlo = xv.x * si + (alo - zp.x * si);
            float zhi = xv.y * si + (ahi - zp.y * si);
            float rs = rsums[node];
            hout[idx2] = f2_to_h2(zlo * rs, zhi * rs);
        } else {
            float2 z1v = h2_to_f2(ha[idx2]);
            float2 z2v = h2_to_f2(hb[idx2]);
            float2 z3v = h2_to_f2(hin[idx2]);
            float xlo = __builtin_nontemporal_load(&x[idx2 * 2]);
            float xhi = __builtin_nontemporal_load(&x[idx2 * 2 + 1]);
            float rlo = (alo + (2.f * z1v.x + 4.f * z2v.x + z3v.x) * si - 2.f * xlo) * (1.0f / 6.0f);
            float rhi = (ahi + (2.f * z1v.y + 4.f * z2v.y + z3v.y) * si - 2.f * xhi) * (1.0f / 6.0f);
            __builtin_nontemporal_store(rlo, &zout[idx2 * 2]);
            __builtin_nontemporal_store(rhi, &zout[idx2 * 2 + 1]);
        }
    }
}

extern "C" void kernel_launch(void* const* d_in, const int* in_sizes, int n_in,
                              void* d_out, int out_size, void* d_ws, size_t ws_size,
                              hipStream_t stream) {
    const float* x   = (const float*)d_in[0];
    const float* att = (const float*)d_in[1];
    const int*   ei  = (const int*)d_in[2];
    const int E = in_sizes[1];
    const int N = in_sizes[0] / DCH;     // NOTE: src packed in 16 bits -> requires N <= 65536
    const int* src = ei;
    const int* dst = ei + E;

    const int NB  = (N + BKT - 1) / BKT;   // 391
    const int NBG = NB * GBC;
    const int NK2 = 2 * NBG;
    const int EK = E - (int)((long long)(0.2 * (double)(E - 1))) + 64;

    char* ws = (char*)d_ws;
    size_t off = 0;
    auto alloc = [&](size_t b) { size_t o = off; off += (b + 255) & ~(size_t)255; return o; };
    int*    hist2d = (int*)   (ws + alloc((size_t)GB_HIST * NBINS * 4));
    int*    hist   = (int*)   (ws + alloc((size_t)NBINS * 4));
    int*    csum   = (int*)   (ws + alloc(64 * 4));
    Ctrl*   ctrl   = (Ctrl*)  (ws + alloc(256));
    uint2*  cand   = (uint2*) (ws + alloc((size_t)CAP * 8));
    int*    cntAll = (int*)   (ws + alloc((size_t)2 * SUBC * NBG * 4));
    int*    off2d  = (int*)   (ws + alloc(((size_t)NK2 + 1) * 4));
    int*    bsum   = (int*)   (ws + alloc(256 * 4));
    int*    boff   = (int*)   (ws + alloc(256 * 4));
    float*  rsums  = (float*) (ws + alloc((size_t)N * 4));
    float*  sinv   = (float*) (ws + alloc((size_t)N * 4));
    int*    rowp   = (int*)   (ws + alloc(((size_t)N + 1) * 4));
    uint2*  ebufD  = (uint2*) (ws + alloc((size_t)EK * 8));
    unsigned* csr32= (unsigned*)(ws + alloc((size_t)EK * 4));
    unsigned* ebufS= (unsigned*)(ws + alloc((size_t)EK * 4));
    __half* hx     = (__half*)(ws + alloc((size_t)N * DCH * 2));
    __half* h1     = (__half*)(ws + alloc((size_t)N * DCH * 2));
    __half* h2     = (__half*)(ws + alloc((size_t)N * DCH * 2));
    __half* h3     = (__half*)(ws + alloc((size_t)N * DCH * 2));
    float*  out    = (float*)d_out;

    hipMemsetAsync(ctrl, 0, 256, stream);

    // numpy-style quantile index arithmetic (float64)
    double q   = 1.0 - 0.8;
    double pos = q * (double)(E - 1);
    long long i0 = (long long)floor(pos);
    double frac  = pos - (double)i0;
    long long i1 = i0 + 1;
    if (i1 > (long long)E - 1) i1 = (long long)E - 1;

    const int nbscan = (NK2 + SCAN_CH - 1) / SCAN_CH;

    k_hist    <<<GB_HIST, 512, 0, stream>>>(att, E, hist2d);
    k_fold    <<<NBINS / 64, 256, 0, stream>>>(hist2d, hist, csum);
    k_pick    <<<1, 256, 0, stream>>>(hist, csum, ctrl, i0, i1);
    k_countc  <<<GBC * SUBC, 256, 0, stream>>>(att, src, dst, E, NB, NBG, ctrl,
                                               cntAll, cand);
    k_finalize<<<1, 256, 0, stream>>>(ctrl, cand, src, dst, i0, i1, frac,
                                      cntAll, NB, NBG);
    k_scan1   <<<nbscan, 256, 0, stream>>>(cntAll, NB, NBG, NK2, bsum);
    k_scan2   <<<1, 256, 0, stream>>>(bsum, nbscan, boff, off2d, NK2);
    k_scan3   <<<nbscan, 256, 0, stream>>>(cntAll, NB, NBG, NK2, boff, off2d);
    k_scatter <<<GBC, 1024, 0, stream>>>(att, src, dst, E, NB, NBG, ctrl, off2d,
                                         cand, ebufD, ebufS);
    k_sortsum <<<NB, 256, 0, stream>>>(off2d, NBG, ebufS, ebufD, x, rsums, sinv, hx,
                                       csr32, rowp, N);

    dim3 blk(64, 4);
    int nb = (N + 3) / 4;
    unsigned* hxu = (unsigned*)hx;
    unsigned* h1u = (unsigned*)h1;
    unsigned* h2u = (unsigned*)h2;
    unsigned* h3u = (unsigned*)h3;
    k_spmv<<<nb, blk, 0, stream>>>(rowp, csr32, hxu, h1u, hxu, nullptr, nullptr, rsums, sinv, x, nullptr, N, 1);
    k_spmv<<<nb, blk, 0, stream>>>(rowp, csr32, h1u, h2u, hxu, nullptr, nullptr, rsums, sinv, x, nullptr, N, 2);
    k_spmv<<<nb, blk, 0, stream>>>(rowp, csr32, h2u, h3u, hxu, nullptr, nullptr, rsums, sinv, x, nullptr, N, 3);
    k_spmv<<<nb, blk, 0, stream>>>(rowp, csr32, h3u, nullptr, hxu, h1u, h2u, rsums, sinv, x, out, N, 4);
}

// Round 13
// 306.259 us; speedup vs baseline: 1.0906x; 1.0552x over previous
//
#include <hip/hip_runtime.h>
#include <hip/hip_fp16.h>
#include <math.h>

#define NBINS   4096
#define GB_HIST 256     // hist blocks (512 threads each)
#define GBC     256     // scatter slabs == scatter grid
#define SUBC    4       // count sub-blocks per slab
#define CAP     2048
#define DCH     64
#define BKT     128     // nodes per bucket
#define NBMAX   512     // max buckets (N <= 65536)
#define SCAN_CH 2048

#define FLAG_AGG (1u << 30)
#define FLAG_INC (2u << 30)
#define VAL_MASK 0x3FFFFFFFu

struct Ctrl {
    double thr;
    int cand_cnt;
    int b0, b1;
    int base0;
    float s0, s1;
};

__device__ __forceinline__ int bin_of(float v) {
    int b = (int)(v * (float)NBINS);
    if (b < 0) b = 0;
    if (b >= NBINS) b = NBINS - 1;
    return b;
}

union U32H2 { unsigned u; __half2 h; };

__device__ __forceinline__ float2 h2_to_f2(unsigned u) {
    U32H2 c; c.u = u;
    return __half22float2(c.h);
}
__device__ __forceinline__ unsigned f2_to_h2(float a, float b) {
    U32H2 c; c.h = __floats2half2_rn(a, b);
    return c.u;
}
__device__ __forceinline__ float wt_of(unsigned ev) {
    return __half2float(__ushort_as_half((unsigned short)(ev >> 16)));
}

// ---------- LDS histogram, dense (non-atomic) flush. 256 blocks x 512 ----------
__global__ void k_hist(const float* __restrict__ att, int E, int* __restrict__ hist2d) {
    __shared__ int lh[NBINS];   // 16 KB
    int t = threadIdx.x;
    for (int b = t; b < NBINS; b += 512) lh[b] = 0;
    __syncthreads();
    for (int i = blockIdx.x * 512 + t; i < E; i += GB_HIST * 512)
        atomicAdd(&lh[bin_of(att[i])], 1);
    __syncthreads();
    for (int b = t; b < NBINS; b += 512)
        hist2d[blockIdx.x * NBINS + b] = lh[b];
}

// 64 blocks x 256: each block folds 64 bins; 4 threads per bin sum 64 partials each.
__global__ void k_fold(const int* __restrict__ hist2d, int* __restrict__ hist,
                       int* __restrict__ csum) {
    __shared__ int sh[256];
    int t = threadIdx.x;
    int j = blockIdx.x * 64 + (t & 63);
    int p = t >> 6;   // 0..3
    int s = 0;
    for (int q = 0; q < GB_HIST / 4; q++)
        s += hist2d[(p * (GB_HIST / 4) + q) * NBINS + j];
    sh[t] = s;
    __syncthreads();
    if (p == 0) {
        int h = sh[t] + sh[t + 64] + sh[t + 128] + sh[t + 192];
        hist[j] = h;
        int r = h;
        for (int off = 32; off > 0; off >>= 1) r += __shfl_down(r, off, 64);
        if (t == 0) csum[blockIdx.x] = r;
    }
}

// 1 block x 256: scan 64 chunk-sums, then 64 bins in the hit chunks -> b0, b1, base0
__global__ void k_pick(const int* __restrict__ hist, const int* __restrict__ csum,
                       Ctrl* ctrl, long long i0, long long i1) {
    __shared__ int sh[256];
    __shared__ int c0s, c1s;
    __shared__ long long e0s, e1s;
    int t = threadIdx.x;
    int v = (t < 64) ? csum[t] : 0;
    sh[t] = v;
    __syncthreads();
    for (int off = 1; off < 256; off <<= 1) {
        int u = (t >= off) ? sh[t - off] : 0;
        __syncthreads(); sh[t] += u; __syncthreads();
    }
    long long excl = (long long)(sh[t] - v);
    if (t < 64) {
        if (i0 >= excl && i0 < excl + v) { c0s = t; e0s = excl; }
        if (i1 >= excl && i1 < excl + v) { c1s = t; e1s = excl; }
    }
    __syncthreads();
    int c0 = c0s, c1 = c1s;
    long long e0 = e0s, e1 = e1s;

    int hv = (t < 64) ? hist[c0 * 64 + t] : 0;
    sh[t] = hv; __syncthreads();
    for (int off = 1; off < 256; off <<= 1) {
        int u = (t >= off) ? sh[t - off] : 0;
        __syncthreads(); sh[t] += u; __syncthreads();
    }
    long long be = e0 + (long long)(sh[t] - hv);
    if (t < 64 && i0 >= be && i0 < be + hv) { ctrl->b0 = c0 * 64 + t; ctrl->base0 = (int)be; }
    __syncthreads();

    hv = (t < 64) ? hist[c1 * 64 + t] : 0;
    sh[t] = hv; __syncthreads();
    for (int off = 1; off < 256; off <<= 1) {
        int u = (t >= off) ? sh[t - off] : 0;
        __syncthreads(); sh[t] += u; __syncthreads();
    }
    be = e1 + (long long)(sh[t] - hv);
    if (t < 64 && i1 >= be && i1 < be + hv) { ctrl->b1 = c1 * 64 + t; }
}

// ---------- count + candidate collect: GBC*SUBC blocks x 256 ----------
__global__ void k_countc(const float* __restrict__ att, const int* __restrict__ src,
                         const int* __restrict__ dst, int E, int NB, int NBG,
                         Ctrl* __restrict__ ctrl, int* __restrict__ cntAll,
                         uint2* __restrict__ cand) {
    __shared__ int lD[NBMAX], lS[NBMAX];
    int t = threadIdx.x;
    for (int b = t; b < NB; b += 256) { lD[b] = 0; lS[b] = 0; }
    __syncthreads();
    int bb = blockIdx.x;
    int k = bb & (GBC - 1);
    int s = bb >> 8;            // GBC = 256
    int b0 = ctrl->b0, b1 = ctrl->b1;
    for (int c = k + GBC * s; c * 1024 < E; c += GBC * SUBC) {
        int base = c * 1024;
        for (int u = t; u < 1024; u += 256) {
            int i = base + u;
            if (i < E) {
                float v = att[i];
                int bin = bin_of(v);
                if (bin > b1) {
                    atomicAdd(&lD[dst[i] >> 7], 1);
                    atomicAdd(&lS[src[i] >> 7], 1);
                } else if (bin >= b0) {
                    int idx = atomicAdd(&ctrl->cand_cnt, 1);
                    if (idx < CAP) {
                        uint2 cv; cv.x = (unsigned)i; cv.y = __float_as_uint(v);
                        cand[idx] = cv;
                    }
                }
            }
        }
    }
    __syncthreads();
    int dbase = (s * GBC + k) * NB;
    for (int b = t; b < NB; b += 256) {
        cntAll[dbase + b]              = lD[b];
        cntAll[SUBC * NBG + dbase + b] = lS[b];
    }
}

// 1 block: exact rank among candidates -> thr (numpy f64 lerp); then add kept
// candidates into cntAll (sub-slot 0) so the scans see exact totals.
__global__ void k_finalize(Ctrl* ctrl, const uint2* __restrict__ cand,
                           const int* __restrict__ src, const int* __restrict__ dst,
                           long long i0, long long i1, double frac,
                           int* __restrict__ cntAll, int NB, int NBG) {
    __shared__ float shv[CAP];
    __shared__ float s0s, s1s;
    __shared__ double thrS;
    int n = ctrl->cand_cnt;
    if (n > CAP) n = CAP;
    int t = threadIdx.x;
    for (int i = t; i < n; i += 256) shv[i] = __uint_as_float(cand[i].y);
    __syncthreads();
    int r0 = (int)(i0 - (long long)ctrl->base0);
    int r1 = (int)(i1 - (long long)ctrl->base0);
    for (int i = t; i < n; i += 256) {
        float v = shv[i];
        int rank = 0;
        for (int j = 0; j < n; j++) {
            float u = shv[j];
            rank += (u < v) || (u == v && j < i);   // stable tie-break => unique ranks
        }
        if (rank == r0) s0s = v;
        if (rank == r1) s1s = v;
    }
    __syncthreads();
    if (t == 0) {
        double a = (double)s0s, b = (double)s1s;
        double thr = b - (b - a) * (1.0 - frac);   // numpy _lerp, t>=0.5 branch
        ctrl->thr = thr; thrS = thr;
        ctrl->s0 = s0s; ctrl->s1 = s1s;
    }
    __syncthreads();
    double thr = thrS;
    for (int i = t; i < n; i += 256) {
        float v = shv[i];
        if ((double)v > thr) {
            int e = (int)cand[i].x;
            int k = (e >> 10) & (GBC - 1);
            atomicAdd(&cntAll[k * NB + (dst[e] >> 7)], 1);
            atomicAdd(&cntAll[SUBC * NBG + k * NB + (src[e] >> 7)], 1);
        }
    }
}

// scan domain j in [0, 2*NBG): (half, bucket=r>>8, blk=r&255); sum SUBC sub-counts
__device__ __forceinline__ int cnt_at(const int* cntAll, int j, int NB, int NBG) {
    int half = (j >= NBG) ? 1 : 0;
    int r = j - half * NBG;
    int b = r >> 8;
    int k = r & (GBC - 1);
    const int* p = cntAll + half * SUBC * NBG + k * NB + b;
    int s = 0;
    #pragma unroll
    for (int q = 0; q < SUBC; q++) s += p[q * GBC * NB];
    return s;
}

// ---------- single-pass scan with decoupled lookback (all blocks co-resident) ----------
__global__ void k_scanAll(const int* __restrict__ cntAll, int NB, int NBG, int NK2,
                          int* __restrict__ off2d, unsigned* __restrict__ state) {
    __shared__ int sh[256];
    __shared__ int exclS;
    int b = blockIdx.x, t = threadIdx.x;
    int j0 = b * SCAN_CH + t * 8;
    int v[8];
    int ts = 0;
    for (int u = 0; u < 8; u++) {
        int j = j0 + u;
        v[u] = (j < NK2) ? cnt_at(cntAll, j, NB, NBG) : 0;
        ts += v[u];
    }
    sh[t] = ts;
    __syncthreads();
    for (int off = 1; off < 256; off <<= 1) {
        int u = (t >= off) ? sh[t - off] : 0;
        __syncthreads(); sh[t] += u; __syncthreads();
    }
    int blockTotal = sh[255];
    if (t == 0) {
        atomicExch(&state[b], FLAG_AGG | (unsigned)blockTotal);
        int excl = 0;
        int p = b - 1;
        while (p >= 0) {
            unsigned s;
            do { s = atomicAdd(&state[p], 0u); } while ((s & 0xC0000000u) == 0u);
            excl += (int)(s & VAL_MASK);
            if (s & FLAG_INC) break;
            p--;
        }
        atomicExch(&state[b], FLAG_INC | (unsigned)(excl + blockTotal));
        exclS = excl;
        if (b == (int)gridDim.x - 1) off2d[NK2] = excl + blockTotal;
    }
    __syncthreads();
    int excl = exclS + sh[t] - ts;
    for (int u = 0; u < 8; u++) {
        int j = j0 + u;
        if (j < NK2) off2d[j] = excl;
        excl += v[u];
    }
}

// ---------- scatter: GBC blocks x 1024 threads; main (bin>b1) + candidate tail ----------
__global__ __launch_bounds__(1024) void k_scatter(
    const float* __restrict__ att, const int* __restrict__ src,
    const int* __restrict__ dst, int E, int NB, int NBG,
    const Ctrl* __restrict__ ctrl, const int* __restrict__ off2d,
    const uint2* __restrict__ cand,
    uint2* __restrict__ ebufD, unsigned* __restrict__ ebufS) {
    __shared__ int baseD[NBMAX], baseS[NBMAX], fD[NBMAX], fS[NBMAX];
    int t = threadIdx.x;
    int K = off2d[NBG];
    for (int b = t; b < NB; b += 1024) {
        baseD[b] = off2d[b * GBC + blockIdx.x];
        baseS[b] = off2d[NBG + b * GBC + blockIdx.x] - K;
        fD[b] = 0; fS[b] = 0;
    }
    __syncthreads();
    int b1 = ctrl->b1;
    for (int i = blockIdx.x * 1024 + t; i < E; i += GBC * 1024) {
        float v = att[i];
        if (bin_of(v) > b1) {
            int s = src[i], d = dst[i];
            int bD = d >> 7, bS = s >> 7;
            int pD = baseD[bD] + atomicAdd(&fD[bD], 1);
            uint2 ev; ev.x = (unsigned)s | ((unsigned)(d & 127) << 16);
            ev.y = __float_as_uint(v);
            ebufD[pD] = ev;
            int pS = baseS[bS] + atomicAdd(&fS[bS], 1);
            unsigned hv = (unsigned)__half_as_ushort(__float2half(v));
            ebufS[pS] = hv | ((unsigned)(s & 127) << 16);
        }
    }
    // candidate tail: place kept candidates belonging to this slab
    double thr = ctrl->thr;
    int nc = ctrl->cand_cnt;
    if (nc > CAP) nc = CAP;
    for (int e = t; e < nc; e += 1024) {
        uint2 cv = cand[e];
        int i = (int)cv.x;
        if (((i >> 10) & (GBC - 1)) != (int)blockIdx.x) continue;
        float v = __uint_as_float(cv.y);
        if ((double)v > thr) {
            int s = src[i], d = dst[i];
            int bD = d >> 7, bS = s >> 7;
            int pD = baseD[bD] + atomicAdd(&fD[bD], 1);
            uint2 ev; ev.x = (unsigned)s | ((unsigned)(d & 127) << 16);
            ev.y = __float_as_uint(v);
            ebufD[pD] = ev;
            int pS = baseS[bS] + atomicAdd(&fS[bS], 1);
            unsigned hv = (unsigned)__half_as_ushort(__float2half(v));
            ebufS[pS] = hv | ((unsigned)(s & 127) << 16);
        }
    }
}

// ---------- fused per-bucket (128 nodes): src-segment sums -> rs, sinv;
//            hx = f16(x*rs); dst-segment counting sort -> packed CSR + rowp ----------
__global__ __launch_bounds__(256) void k_sortsum(
    const int* __restrict__ off2d, int NBG,
    const unsigned* __restrict__ ebufS, const uint2* __restrict__ ebufD,
    const float* __restrict__ x, float* __restrict__ rsums, float* __restrict__ sinv,
    __half* __restrict__ hx,
    unsigned* __restrict__ csr, int* __restrict__ rowp, int N) {
    __shared__ float s128[BKT];
    __shared__ float r128[BKT];
    __shared__ int cnt[BKT], basea[BKT + 1], fill[BKT];
    int b = blockIdx.x, t = threadIdx.x;
    if (t < BKT) { s128[t] = 0.f; cnt[t] = 0; fill[t] = 0; }
    __syncthreads();
    int K = off2d[NBG];
    int slo = off2d[NBG + b * GBC] - K;
    int shi = off2d[NBG + (b + 1) * GBC] - K;
    for (int e = slo + t; e < shi; e += 256) {
        unsigned u = ebufS[e];
        atomicAdd(&s128[(u >> 16) & 127],
                  __half2float(__ushort_as_half((unsigned short)(u & 0xFFFFu))));
    }
    int dlo = off2d[b * GBC], dhi = off2d[(b + 1) * GBC];
    for (int e = dlo + t; e < dhi; e += 256)
        atomicAdd(&cnt[(ebufD[e].x >> 16) & 127], 1);
    __syncthreads();
    if (t < BKT) {
        float sv = (s128[t] > 0.f) ? (s128[t] + 1e-16f) : 1.0f;
        float r = 1.f / sv;
        r128[t] = r;
        int node = b * BKT + t;
        if (node < N) { rsums[node] = r; sinv[node] = sv; }
    }
    if (t == 0) {
        int s = 0;
        for (int i = 0; i < BKT; i++) { basea[i] = s; s += cnt[i]; }
        basea[BKT] = s;
    }
    __syncthreads();
    if (t <= BKT) {
        int node = b * BKT + t;
        if (node <= N) rowp[node] = dlo + basea[t];
    }
    int xbase = b * BKT * DCH;
    for (int i = t; i < BKT * DCH; i += 256) {
        int node = b * BKT + (i >> 6);
        if (node < N) hx[xbase + i] = __float2half(x[xbase + i] * r128[i >> 6]);
    }
    for (int e = dlo + t; e < dhi; e += 256) {
        uint2 ev = ebufD[e];
        int dl = (ev.x >> 16) & 127;
        int pos = dlo + basea[dl] + atomicAdd(&fill[dl], 1);
        unsigned hb = (unsigned)__half_as_ushort(__float2half(__uint_as_float(ev.y)));
        csr[pos] = (ev.x & 0xFFFFu) | (hb << 16);
    }
}

// ---------- spmv: quarter-wave uint2 gather; 4 edges per j-group ----------
// lane = (edge-slot h = lane>>4 in 0..3, word c = lane&15). One uint2 load = channels
// 4c..4c+3. A j-step covers 16 edges (4 per slot). Butterfly xor(16),xor(32) reduce;
// epilogue on 16 lanes with uint2 state words.
// state recovery: z = h * sinv  (h = f16(z*rs), rs = 1/sinv)
__global__ __launch_bounds__(256) void k_spmv(
    const int* __restrict__ rowp, const unsigned* __restrict__ csr,
    const uint2* __restrict__ hin, uint2* __restrict__ hout,
    const uint2* __restrict__ hxb, const uint2* __restrict__ ha,
    const uint2* __restrict__ hb,
    const float* __restrict__ rsums, const float* __restrict__ sinv,
    const float* __restrict__ x, float* __restrict__ zout,
    int N, int pass)
{
    int node = blockIdx.x * 4 + threadIdx.y;
    if (node >= N) return;
    int lane = threadIdx.x;
    int h = lane >> 4;        // edge slot 0..3
    int c = lane & 15;        // uint2 word index (channels 4c..4c+3)
    int beg = rowp[node], end = rowp[node + 1];

    float a0[4] = {0.f, 0.f, 0.f, 0.f};
    float a1[4] = {0.f, 0.f, 0.f, 0.f};
    float a2[4] = {0.f, 0.f, 0.f, 0.f};
    float a3[4] = {0.f, 0.f, 0.f, 0.f};
    for (int e = beg; e < end; e += 64) {
        int m = end - e;
        if (m > 64) m = 64;
        unsigned ev = 0;
        if (lane < m) ev = __builtin_nontemporal_load(&csr[e + lane]);
        for (int j = 0; j < m; j += 16) {
            #pragma unroll
            for (int q = 0; q < 4; q++) {
                int s = j + q * 4 + h;            // <= 63 always
                unsigned v = (unsigned)__shfl((int)ev, s, 64);
                uint2 z = hin[(v & 0xFFFFu) * 16 + c];   // masked lanes: ev=0 -> row 0
                float w = (s < m) ? wt_of(v) : 0.f;
                float2 fa = h2_to_f2(z.x);
                float2 fb = h2_to_f2(z.y);
                a0[q] = fmaf(w, fa.x, a0[q]);
                a1[q] = fmaf(w, fa.y, a1[q]);
                a2[q] = fmaf(w, fb.x, a2[q]);
                a3[q] = fmaf(w, fb.y, a3[q]);
            }
        }
    }
    float s0 = (a0[0] + a0[1]) + (a0[2] + a0[3]);
    float s1 = (a1[0] + a1[1]) + (a1[2] + a1[3]);
    float s2 = (a2[0] + a2[1]) + (a2[2] + a2[3]);
    float s3 = (a3[0] + a3[1]) + (a3[2] + a3[3]);
    s0 += __shfl_xor(s0, 16, 64);  s0 += __shfl_xor(s0, 32, 64);
    s1 += __shfl_xor(s1, 16, 64);  s1 += __shfl_xor(s1, 32, 64);
    s2 += __shfl_xor(s2, 16, 64);  s2 += __shfl_xor(s2, 32, 64);
    s3 += __shfl_xor(s3, 16, 64);  s3 += __shfl_xor(s3, 32, 64);

    if (h == 0) {
        int idx = node * 16 + c;
        float si = sinv[node];
        if (pass == 1) {
            uint2 xw = hin[idx];
            float2 xa = h2_to_f2(xw.x), xb = h2_to_f2(xw.y);
            float z0 = 0.5f * (s0 + xa.x * si);
            float z1 = 0.5f * (s1 + xa.y * si);
            float z2 = 0.5f * (s2 + xb.x * si);
            float z3 = 0.5f * (s3 + xb.y * si);
            float rs = rsums[node];
            uint2 o; o.x = f2_to_h2(z0 * rs, z1 * rs); o.y = f2_to_h2(z2 * rs, z3 * rs);
            hout[idx] = o;
        } else if (pass == 2) {
            uint2 xw = hxb[idx], zw = hin[idx];
            float2 xa = h2_to_f2(xw.x), xb = h2_to_f2(xw.y);
            float2 za = h2_to_f2(zw.x), zb = h2_to_f2(zw.y);
            float z0 = xa.x * si + 0.5f * (s0 - za.x * si);
            float z1 = xa.y * si + 0.5f * (s1 - za.y * si);
            float z2 = xb.x * si + 0.5f * (s2 - zb.x * si);
            float z3 = xb.y * si + 0.5f * (s3 - zb.y * si);
            float rs = rsums[node];
            uint2 o; o.x = f2_to_h2(z0 * rs, z1 * rs); o.y = f2_to_h2(z2 * rs, z3 * rs);
            hout[idx] = o;
        } else if (pass == 3) {
            uint2 xw = hxb[idx], zw = hin[idx];
            float2 xa = h2_to_f2(xw.x), xb = h2_to_f2(xw.y);
            float2 za = h2_to_f2(zw.x), zb = h2_to_f2(zw.y);
            float z0 = xa.x * si + (s0 - za.x * si);
            float z1 = xa.y * si + (s1 - za.y * si);
            float z2 = xb.x * si + (s2 - zb.x * si);
            float z3 = xb.y * si + (s3 - zb.y * si);
            float rs = rsums[node];
            uint2 o; o.x = f2_to_h2(z0 * rs, z1 * rs); o.y = f2_to_h2(z2 * rs, z3 * rs);
            hout[idx] = o;
        } else {
            uint2 w1 = ha[idx], w2 = hb[idx], w3 = hin[idx];
            float2 z1a = h2_to_f2(w1.x), z1b = h2_to_f2(w1.y);
            float2 z2a = h2_to_f2(w2.x), z2b = h2_to_f2(w2.y);
            float2 z3a = h2_to_f2(w3.x), z3b = h2_to_f2(w3.y);
            int fb2 = node * DCH + c * 4;
            float x0 = __builtin_nontemporal_load(&x[fb2]);
            float x1 = __builtin_nontemporal_load(&x[fb2 + 1]);
            float x2 = __builtin_nontemporal_load(&x[fb2 + 2]);
            float x3 = __builtin_nontemporal_load(&x[fb2 + 3]);
            float r0 = (s0 + (2.f * z1a.x + 4.f * z2a.x + z3a.x) * si - 2.f * x0) * (1.0f / 6.0f);
            float r1 = (s1 + (2.f * z1a.y + 4.f * z2a.y + z3a.y) * si - 2.f * x1) * (1.0f / 6.0f);
            float r2 = (s2 + (2.f * z1b.x + 4.f * z2b.x + z3b.x) * si - 2.f * x2) * (1.0f / 6.0f);
            float r3 = (s3 + (2.f * z1b.y + 4.f * z2b.y + z3b.y) * si - 2.f * x3) * (1.0f / 6.0f);
            __builtin_nontemporal_store(r0, &zout[fb2]);
            __builtin_nontemporal_store(r1, &zout[fb2 + 1]);
            __builtin_nontemporal_store(r2, &zout[fb2 + 2]);
            __builtin_nontemporal_store(r3, &zout[fb2 + 3]);
        }
    }
}

extern "C" void kernel_launch(void* const* d_in, const int* in_sizes, int n_in,
                              void* d_out, int out_size, void* d_ws, size_t ws_size,
                              hipStream_t stream) {
    const float* x   = (const float*)d_in[0];
    const float* att = (const float*)d_in[1];
    const int*   ei  = (const int*)d_in[2];
    const int E = in_sizes[1];
    const int N = in_sizes[0] / DCH;     // NOTE: src packed in 16 bits -> requires N <= 65536
    const int* src = ei;
    const int* dst = ei + E;

    const int NB  = (N + BKT - 1) / BKT;   // 391
    const int NBG = NB * GBC;
    const int NK2 = 2 * NBG;
    const int EK = E - (int)((long long)(0.2 * (double)(E - 1))) + 64;

    char* ws = (char*)d_ws;
    size_t off = 0;
    auto alloc = [&](size_t b) { size_t o = off; off += (b + 255) & ~(size_t)255; return o; };
    int*    hist2d = (int*)   (ws + alloc((size_t)GB_HIST * NBINS * 4));
    int*    hist   = (int*)   (ws + alloc((size_t)NBINS * 4));
    int*    csum   = (int*)   (ws + alloc(64 * 4));
    // zero region: ctrl + scan state (one memset)
    size_t zbeg = off;
    Ctrl*   ctrl   = (Ctrl*)  (ws + alloc(256));
    unsigned* sstate = (unsigned*)(ws + alloc(512));
    size_t zlen = off - zbeg;
    uint2*  cand   = (uint2*) (ws + alloc((size_t)CAP * 8));
    int*    cntAll = (int*)   (ws + alloc((size_t)2 * SUBC * NBG * 4));
    int*    off2d  = (int*)   (ws + alloc(((size_t)NK2 + 1) * 4));
    float*  rsums  = (float*) (ws + alloc((size_t)N * 4));
    float*  sinv   = (float*) (ws + alloc((size_t)N * 4));
    int*    rowp   = (int*)   (ws + alloc(((size_t)N + 1) * 4));
    uint2*  ebufD  = (uint2*) (ws + alloc((size_t)EK * 8));
    unsigned* csr32= (unsigned*)(ws + alloc((size_t)EK * 4));
    unsigned* ebufS= (unsigned*)(ws + alloc((size_t)EK * 4));
    __half* hx     = (__half*)(ws + alloc((size_t)N * DCH * 2));
    __half* h1     = (__half*)(ws + alloc((size_t)N * DCH * 2));
    __half* h2     = (__half*)(ws + alloc((size_t)N * DCH * 2));
    __half* h3     = (__half*)(ws + alloc((size_t)N * DCH * 2));
    float*  out    = (float*)d_out;

    hipMemsetAsync(ws + zbeg, 0, zlen, stream);

    // numpy-style quantile index arithmetic (float64)
    double q   = 1.0 - 0.8;
    double pos = q * (double)(E - 1);
    long long i0 = (long long)floor(pos);
    double frac  = pos - (double)i0;
    long long i1 = i0 + 1;
    if (i1 > (long long)E - 1) i1 = (long long)E - 1;

    const int nbscan = (NK2 + SCAN_CH - 1) / SCAN_CH;   // 98 blocks, all co-resident

    k_hist    <<<GB_HIST, 512, 0, stream>>>(att, E, hist2d);
    k_fold    <<<NBINS / 64, 256, 0, stream>>>(hist2d, hist, csum);
    k_pick    <<<1, 256, 0, stream>>>(hist, csum, ctrl, i0, i1);
    k_countc  <<<GBC * SUBC, 256, 0, stream>>>(att, src, dst, E, NB, NBG, ctrl,
                                               cntAll, cand);
    k_finalize<<<1, 256, 0, stream>>>(ctrl, cand, src, dst, i0, i1, frac,
                                      cntAll, NB, NBG);
    k_scanAll <<<nbscan, 256, 0, stream>>>(cntAll, NB, NBG, NK2, off2d, sstate);
    k_scatter <<<GBC, 1024, 0, stream>>>(att, src, dst, E, NB, NBG, ctrl, off2d,
                                         cand, ebufD, ebufS);
    k_sortsum <<<NB, 256, 0, stream>>>(off2d, NBG, ebufS, ebufD, x, rsums, sinv, hx,
                                       csr32, rowp, N);

    dim3 blk(64, 4);
    int nb = (N + 3) / 4;
    uint2* hxu = (uint2*)hx;
    uint2* h1u = (uint2*)h1;
    uint2* h2u = (uint2*)h2;
    uint2* h3u = (uint2*)h3;
    k_spmv<<<nb, blk, 0, stream>>>(rowp, csr32, hxu, h1u, hxu, nullptr, nullptr, rsums, sinv, x, nullptr, N, 1);
    k_spmv<<<nb, blk, 0, stream>>>(rowp, csr32, h1u, h2u, hxu, nullptr, nullptr, rsums, sinv, x, nullptr, N, 2);
    k_spmv<<<nb, blk, 0, stream>>>(rowp, csr32, h2u, h3u, hxu, nullptr, nullptr, rsums, sinv, x, nullptr, N, 3);
    k_spmv<<<nb, blk, 0, stream>>>(rowp, csr32, h3u, nullptr, hxu, h1u, h2u, rsums, sinv, x, out, N, 4);
}

// Round 14
// 292.632 us; speedup vs baseline: 1.1414x; 1.0466x over previous
//
#include <hip/hip_runtime.h>
#include <hip/hip_fp16.h>
#include <math.h>

#define NBINS   4096
#define GB_HIST 256     // hist blocks (512 threads each)
#define GBC     256     // scatter slabs == scatter grid
#define SUBC    4       // count sub-blocks per slab
#define CAP     2048
#define DCH     64
#define BKT     128     // nodes per bucket
#define NBMAX   512     // max buckets (N <= 65536)
#define SCAN_CH 2048

#define FLAG_AGG (1u << 30)
#define FLAG_INC (2u << 30)
#define VAL_MASK 0x3FFFFFFFu

struct Ctrl {
    double thr;
    int cand_cnt;
    int b0, b1;
    int base0;
    float s0, s1;
};

__device__ __forceinline__ int bin_of(float v) {
    int b = (int)(v * (float)NBINS);
    if (b < 0) b = 0;
    if (b >= NBINS) b = NBINS - 1;
    return b;
}

union U32H2 { unsigned u; __half2 h; };

__device__ __forceinline__ float2 h2_to_f2(unsigned u) {
    U32H2 c; c.u = u;
    return __half22float2(c.h);
}
__device__ __forceinline__ unsigned f2_to_h2(float a, float b) {
    U32H2 c; c.h = __floats2half2_rn(a, b);
    return c.u;
}
__device__ __forceinline__ float wt_of(unsigned ev) {
    return __half2float(__ushort_as_half((unsigned short)(ev >> 16)));
}

// ---------- LDS histogram, dense (non-atomic) flush. 256 blocks x 512 ----------
__global__ void k_hist(const float* __restrict__ att, int E, int* __restrict__ hist2d) {
    __shared__ int lh[NBINS];   // 16 KB
    int t = threadIdx.x;
    for (int b = t; b < NBINS; b += 512) lh[b] = 0;
    __syncthreads();
    for (int i = blockIdx.x * 512 + t; i < E; i += GB_HIST * 512)
        atomicAdd(&lh[bin_of(att[i])], 1);
    __syncthreads();
    for (int b = t; b < NBINS; b += 512)
        hist2d[blockIdx.x * NBINS + b] = lh[b];
}

// 64 blocks x 256: each block folds 64 bins; 4 threads per bin sum 64 partials each.
__global__ void k_fold(const int* __restrict__ hist2d, int* __restrict__ hist,
                       int* __restrict__ csum) {
    __shared__ int sh[256];
    int t = threadIdx.x;
    int j = blockIdx.x * 64 + (t & 63);
    int p = t >> 6;   // 0..3
    int s = 0;
    for (int q = 0; q < GB_HIST / 4; q++)
        s += hist2d[(p * (GB_HIST / 4) + q) * NBINS + j];
    sh[t] = s;
    __syncthreads();
    if (p == 0) {
        int h = sh[t] + sh[t + 64] + sh[t + 128] + sh[t + 192];
        hist[j] = h;
        int r = h;
        for (int off = 32; off > 0; off >>= 1) r += __shfl_down(r, off, 64);
        if (t == 0) csum[blockIdx.x] = r;
    }
}

// 1 block x 256: scan 64 chunk-sums, then 64 bins in the hit chunks -> b0, b1, base0
__global__ void k_pick(const int* __restrict__ hist, const int* __restrict__ csum,
                       Ctrl* ctrl, long long i0, long long i1) {
    __shared__ int sh[256];
    __shared__ int c0s, c1s;
    __shared__ long long e0s, e1s;
    int t = threadIdx.x;
    int v = (t < 64) ? csum[t] : 0;
    sh[t] = v;
    __syncthreads();
    for (int off = 1; off < 256; off <<= 1) {
        int u = (t >= off) ? sh[t - off] : 0;
        __syncthreads(); sh[t] += u; __syncthreads();
    }
    long long excl = (long long)(sh[t] - v);
    if (t < 64) {
        if (i0 >= excl && i0 < excl + v) { c0s = t; e0s = excl; }
        if (i1 >= excl && i1 < excl + v) { c1s = t; e1s = excl; }
    }
    __syncthreads();
    int c0 = c0s, c1 = c1s;
    long long e0 = e0s, e1 = e1s;

    int hv = (t < 64) ? hist[c0 * 64 + t] : 0;
    sh[t] = hv; __syncthreads();
    for (int off = 1; off < 256; off <<= 1) {
        int u = (t >= off) ? sh[t - off] : 0;
        __syncthreads(); sh[t] += u; __syncthreads();
    }
    long long be = e0 + (long long)(sh[t] - hv);
    if (t < 64 && i0 >= be && i0 < be + hv) { ctrl->b0 = c0 * 64 + t; ctrl->base0 = (int)be; }
    __syncthreads();

    hv = (t < 64) ? hist[c1 * 64 + t] : 0;
    sh[t] = hv; __syncthreads();
    for (int off = 1; off < 256; off <<= 1) {
        int u = (t >= off) ? sh[t - off] : 0;
        __syncthreads(); sh[t] += u; __syncthreads();
    }
    be = e1 + (long long)(sh[t] - hv);
    if (t < 64 && i1 >= be && i1 < be + hv) { ctrl->b1 = c1 * 64 + t; }
}

// ---------- count + candidate collect: GBC*SUBC blocks x 256 ----------
__global__ void k_countc(const float* __restrict__ att, const int* __restrict__ src,
                         const int* __restrict__ dst, int E, int NB, int NBG,
                         Ctrl* __restrict__ ctrl, int* __restrict__ cntAll,
                         uint2* __restrict__ cand) {
    __shared__ int lD[NBMAX], lS[NBMAX];
    int t = threadIdx.x;
    for (int b = t; b < NB; b += 256) { lD[b] = 0; lS[b] = 0; }
    __syncthreads();
    int bb = blockIdx.x;
    int k = bb & (GBC - 1);
    int s = bb >> 8;            // GBC = 256
    int b0 = ctrl->b0, b1 = ctrl->b1;
    for (int c = k + GBC * s; c * 1024 < E; c += GBC * SUBC) {
        int base = c * 1024;
        for (int u = t; u < 1024; u += 256) {
            int i = base + u;
            if (i < E) {
                float v = att[i];
                int bin = bin_of(v);
                if (bin > b1) {
                    atomicAdd(&lD[dst[i] >> 7], 1);
                    atomicAdd(&lS[src[i] >> 7], 1);
                } else if (bin >= b0) {
                    int idx = atomicAdd(&ctrl->cand_cnt, 1);
                    if (idx < CAP) {
                        uint2 cv; cv.x = (unsigned)i; cv.y = __float_as_uint(v);
                        cand[idx] = cv;
                    }
                }
            }
        }
    }
    __syncthreads();
    int dbase = (s * GBC + k) * NB;
    for (int b = t; b < NB; b += 256) {
        cntAll[dbase + b]              = lD[b];
        cntAll[SUBC * NBG + dbase + b] = lS[b];
    }
}

// 1 block: exact rank among candidates -> thr (numpy f64 lerp); then add kept
// candidates into cntAll (sub-slot 0) so the scans see exact totals.
__global__ void k_finalize(Ctrl* ctrl, const uint2* __restrict__ cand,
                           const int* __restrict__ src, const int* __restrict__ dst,
                           long long i0, long long i1, double frac,
                           int* __restrict__ cntAll, int NB, int NBG) {
    __shared__ float shv[CAP];
    __shared__ float s0s, s1s;
    __shared__ double thrS;
    int n = ctrl->cand_cnt;
    if (n > CAP) n = CAP;
    int t = threadIdx.x;
    for (int i = t; i < n; i += 256) shv[i] = __uint_as_float(cand[i].y);
    __syncthreads();
    int r0 = (int)(i0 - (long long)ctrl->base0);
    int r1 = (int)(i1 - (long long)ctrl->base0);
    for (int i = t; i < n; i += 256) {
        float v = shv[i];
        int rank = 0;
        for (int j = 0; j < n; j++) {
            float u = shv[j];
            rank += (u < v) || (u == v && j < i);   // stable tie-break => unique ranks
        }
        if (rank == r0) s0s = v;
        if (rank == r1) s1s = v;
    }
    __syncthreads();
    if (t == 0) {
        double a = (double)s0s, b = (double)s1s;
        double thr = b - (b - a) * (1.0 - frac);   // numpy _lerp, t>=0.5 branch
        ctrl->thr = thr; thrS = thr;
        ctrl->s0 = s0s; ctrl->s1 = s1s;
    }
    __syncthreads();
    double thr = thrS;
    for (int i = t; i < n; i += 256) {
        float v = shv[i];
        if ((double)v > thr) {
            int e = (int)cand[i].x;
            int k = (e >> 10) & (GBC - 1);
            atomicAdd(&cntAll[k * NB + (dst[e] >> 7)], 1);
            atomicAdd(&cntAll[SUBC * NBG + k * NB + (src[e] >> 7)], 1);
        }
    }
}

// scan domain j in [0, 2*NBG): (half, bucket=r>>8, blk=r&255); sum SUBC sub-counts
__device__ __forceinline__ int cnt_at(const int* cntAll, int j, int NB, int NBG) {
    int half = (j >= NBG) ? 1 : 0;
    int r = j - half * NBG;
    int b = r >> 8;
    int k = r & (GBC - 1);
    const int* p = cntAll + half * SUBC * NBG + k * NB + b;
    int s = 0;
    #pragma unroll
    for (int q = 0; q < SUBC; q++) s += p[q * GBC * NB];
    return s;
}

// ---------- single-pass scan with decoupled lookback (all blocks co-resident) ----------
__global__ void k_scanAll(const int* __restrict__ cntAll, int NB, int NBG, int NK2,
                          int* __restrict__ off2d, unsigned* __restrict__ state) {
    __shared__ int sh[256];
    __shared__ int exclS;
    int b = blockIdx.x, t = threadIdx.x;
    int j0 = b * SCAN_CH + t * 8;
    int v[8];
    int ts = 0;
    for (int u = 0; u < 8; u++) {
        int j = j0 + u;
        v[u] = (j < NK2) ? cnt_at(cntAll, j, NB, NBG) : 0;
        ts += v[u];
    }
    sh[t] = ts;
    __syncthreads();
    for (int off = 1; off < 256; off <<= 1) {
        int u = (t >= off) ? sh[t - off] : 0;
        __syncthreads(); sh[t] += u; __syncthreads();
    }
    int blockTotal = sh[255];
    if (t == 0) {
        atomicExch(&state[b], FLAG_AGG | (unsigned)blockTotal);
        int excl = 0;
        int p = b - 1;
        while (p >= 0) {
            unsigned s;
            do { s = atomicAdd(&state[p], 0u); } while ((s & 0xC0000000u) == 0u);
            excl += (int)(s & VAL_MASK);
            if (s & FLAG_INC) break;
            p--;
        }
        atomicExch(&state[b], FLAG_INC | (unsigned)(excl + blockTotal));
        exclS = excl;
        if (b == (int)gridDim.x - 1) off2d[NK2] = excl + blockTotal;
    }
    __syncthreads();
    int excl = exclS + sh[t] - ts;
    for (int u = 0; u < 8; u++) {
        int j = j0 + u;
        if (j < NK2) off2d[j] = excl;
        excl += v[u];
    }
}

// ---------- scatter: GBC blocks x 1024 threads; main (bin>b1) + candidate tail ----------
__global__ __launch_bounds__(1024) void k_scatter(
    const float* __restrict__ att, const int* __restrict__ src,
    const int* __restrict__ dst, int E, int NB, int NBG,
    const Ctrl* __restrict__ ctrl, const int* __restrict__ off2d,
    const uint2* __restrict__ cand,
    uint2* __restrict__ ebufD, unsigned* __restrict__ ebufS) {
    __shared__ int baseD[NBMAX], baseS[NBMAX], fD[NBMAX], fS[NBMAX];
    int t = threadIdx.x;
    int K = off2d[NBG];
    for (int b = t; b < NB; b += 1024) {
        baseD[b] = off2d[b * GBC + blockIdx.x];
        baseS[b] = off2d[NBG + b * GBC + blockIdx.x] - K;
        fD[b] = 0; fS[b] = 0;
    }
    __syncthreads();
    int b1 = ctrl->b1;
    for (int i = blockIdx.x * 1024 + t; i < E; i += GBC * 1024) {
        float v = att[i];
        if (bin_of(v) > b1) {
            int s = src[i], d = dst[i];
            int bD = d >> 7, bS = s >> 7;
            int pD = baseD[bD] + atomicAdd(&fD[bD], 1);
            uint2 ev; ev.x = (unsigned)s | ((unsigned)(d & 127) << 16);
            ev.y = __float_as_uint(v);
            ebufD[pD] = ev;
            int pS = baseS[bS] + atomicAdd(&fS[bS], 1);
            unsigned hv = (unsigned)__half_as_ushort(__float2half(v));
            ebufS[pS] = hv | ((unsigned)(s & 127) << 16);
        }
    }
    // candidate tail: place kept candidates belonging to this slab
    double thr = ctrl->thr;
    int nc = ctrl->cand_cnt;
    if (nc > CAP) nc = CAP;
    for (int e = t; e < nc; e += 1024) {
        uint2 cv = cand[e];
        int i = (int)cv.x;
        if (((i >> 10) & (GBC - 1)) != (int)blockIdx.x) continue;
        float v = __uint_as_float(cv.y);
        if ((double)v > thr) {
            int s = src[i], d = dst[i];
            int bD = d >> 7, bS = s >> 7;
            int pD = baseD[bD] + atomicAdd(&fD[bD], 1);
            uint2 ev; ev.x = (unsigned)s | ((unsigned)(d & 127) << 16);
            ev.y = __float_as_uint(v);
            ebufD[pD] = ev;
            int pS = baseS[bS] + atomicAdd(&fS[bS], 1);
            unsigned hv = (unsigned)__half_as_ushort(__float2half(v));
            ebufS[pS] = hv | ((unsigned)(s & 127) << 16);
        }
    }
}

// ---------- split per-bucket postprocess: 2*NB blocks x 512 ----------
// blocks [0,NB):   src side — ebufS segment sums -> rsums, sinv; hx = f16(x*rs)
// blocks [NB,2NB): dst side — ebufD count -> rowp; counting-sort scatter -> csr
__global__ __launch_bounds__(512) void k_sortsum(
    const int* __restrict__ off2d, int NBG,
    const unsigned* __restrict__ ebufS, const uint2* __restrict__ ebufD,
    const float* __restrict__ x, float* __restrict__ rsums, float* __restrict__ sinv,
    __half* __restrict__ hx,
    unsigned* __restrict__ csr, int* __restrict__ rowp, int N, int NB) {
    __shared__ float s128[BKT];
    __shared__ float r128[BKT];
    __shared__ int cnt[BKT], basea[BKT + 1], fill[BKT];
    int bb = blockIdx.x, t = threadIdx.x;
    if (bb < NB) {
        int b = bb;
        if (t < BKT) s128[t] = 0.f;
        __syncthreads();
        int K = off2d[NBG];
        int slo = off2d[NBG + b * GBC] - K;
        int shi = off2d[NBG + (b + 1) * GBC] - K;
        for (int e = slo + t; e < shi; e += 512) {
            unsigned u = ebufS[e];
            atomicAdd(&s128[(u >> 16) & 127],
                      __half2float(__ushort_as_half((unsigned short)(u & 0xFFFFu))));
        }
        __syncthreads();
        if (t < BKT) {
            float sv = (s128[t] > 0.f) ? (s128[t] + 1e-16f) : 1.0f;
            float r = 1.f / sv;
            r128[t] = r;
            int node = b * BKT + t;
            if (node < N) { rsums[node] = r; sinv[node] = sv; }
        }
        __syncthreads();
        int xbase = b * BKT * DCH;
        for (int i = t; i < BKT * DCH; i += 512) {
            int node = b * BKT + (i >> 6);
            if (node < N) hx[xbase + i] = __float2half(x[xbase + i] * r128[i >> 6]);
        }
    } else {
        int b = bb - NB;
        if (t < BKT) { cnt[t] = 0; fill[t] = 0; }
        __syncthreads();
        int dlo = off2d[b * GBC], dhi = off2d[(b + 1) * GBC];
        for (int e = dlo + t; e < dhi; e += 512)
            atomicAdd(&cnt[(ebufD[e].x >> 16) & 127], 1);
        __syncthreads();
        if (t == 0) {
            int s = 0;
            for (int i = 0; i < BKT; i++) { basea[i] = s; s += cnt[i]; }
            basea[BKT] = s;
        }
        __syncthreads();
        if (t <= BKT) {
            int node = b * BKT + t;
            if (node <= N) rowp[node] = dlo + basea[t];
        }
        for (int e = dlo + t; e < dhi; e += 512) {
            uint2 ev = ebufD[e];
            int dl = (ev.x >> 16) & 127;
            int pos = dlo + basea[dl] + atomicAdd(&fill[dl], 1);
            unsigned hb = (unsigned)__half_as_ushort(__float2half(__uint_as_float(ev.y)));
            csr[pos] = (ev.x & 0xFFFFu) | (hb << 16);
        }
    }
}

// ---------- spmv: quarter-wave uint2 gather; 4 edges per j-group ----------
// lane = (edge-slot h = lane>>4 in 0..3, word c = lane&15). One uint2 load = channels
// 4c..4c+3. A j-step covers 16 edges (4 per slot). Butterfly xor(16),xor(32) reduce;
// epilogue on 16 lanes with uint2 state words.
// state recovery: z = h * sinv  (h = f16(z*rs), rs = 1/sinv)
__global__ __launch_bounds__(256) void k_spmv(
    const int* __restrict__ rowp, const unsigned* __restrict__ csr,
    const uint2* __restrict__ hin, uint2* __restrict__ hout,
    const uint2* __restrict__ hxb, const uint2* __restrict__ ha,
    const uint2* __restrict__ hb,
    const float* __restrict__ rsums, const float* __restrict__ sinv,
    const float* __restrict__ x, float* __restrict__ zout,
    int N, int pass)
{
    int node = blockIdx.x * 4 + threadIdx.y;
    if (node >= N) return;
    int lane = threadIdx.x;
    int h = lane >> 4;        // edge slot 0..3
    int c = lane & 15;        // uint2 word index (channels 4c..4c+3)
    int beg = rowp[node], end = rowp[node + 1];

    float a0[4] = {0.f, 0.f, 0.f, 0.f};
    float a1[4] = {0.f, 0.f, 0.f, 0.f};
    float a2[4] = {0.f, 0.f, 0.f, 0.f};
    float a3[4] = {0.f, 0.f, 0.f, 0.f};
    for (int e = beg; e < end; e += 64) {
        int m = end - e;
        if (m > 64) m = 64;
        unsigned ev = 0;
        if (lane < m) ev = __builtin_nontemporal_load(&csr[e + lane]);
        for (int j = 0; j < m; j += 16) {
            #pragma unroll
            for (int q = 0; q < 4; q++) {
                int s = j + q * 4 + h;            // <= 63 always
                unsigned v = (unsigned)__shfl((int)ev, s, 64);
                uint2 z = hin[(v & 0xFFFFu) * 16 + c];   // masked lanes: ev=0 -> row 0
                float w = (s < m) ? wt_of(v) : 0.f;
                float2 fa = h2_to_f2(z.x);
                float2 fb = h2_to_f2(z.y);
                a0[q] = fmaf(w, fa.x, a0[q]);
                a1[q] = fmaf(w, fa.y, a1[q]);
                a2[q] = fmaf(w, fb.x, a2[q]);
                a3[q] = fmaf(w, fb.y, a3[q]);
            }
        }
    }
    float s0 = (a0[0] + a0[1]) + (a0[2] + a0[3]);
    float s1 = (a1[0] + a1[1]) + (a1[2] + a1[3]);
    float s2 = (a2[0] + a2[1]) + (a2[2] + a2[3]);
    float s3 = (a3[0] + a3[1]) + (a3[2] + a3[3]);
    s0 += __shfl_xor(s0, 16, 64);  s0 += __shfl_xor(s0, 32, 64);
    s1 += __shfl_xor(s1, 16, 64);  s1 += __shfl_xor(s1, 32, 64);
    s2 += __shfl_xor(s2, 16, 64);  s2 += __shfl_xor(s2, 32, 64);
    s3 += __shfl_xor(s3, 16, 64);  s3 += __shfl_xor(s3, 32, 64);

    if (h == 0) {
        int idx = node * 16 + c;
        float si = sinv[node];
        if (pass == 1) {
            uint2 xw = hin[idx];
            float2 xa = h2_to_f2(xw.x), xb = h2_to_f2(xw.y);
            float z0 = 0.5f * (s0 + xa.x * si);
            float z1 = 0.5f * (s1 + xa.y * si);
            float z2 = 0.5f * (s2 + xb.x * si);
            float z3 = 0.5f * (s3 + xb.y * si);
            float rs = rsums[node];
            uint2 o; o.x = f2_to_h2(z0 * rs, z1 * rs); o.y = f2_to_h2(z2 * rs, z3 * rs);
            hout[idx] = o;
        } else if (pass == 2) {
            uint2 xw = hxb[idx], zw = hin[idx];
            float2 xa = h2_to_f2(xw.x), xb = h2_to_f2(xw.y);
            float2 za = h2_to_f2(zw.x), zb = h2_to_f2(zw.y);
            float z0 = xa.x * si + 0.5f * (s0 - za.x * si);
            float z1 = xa.y * si + 0.5f * (s1 - za.y * si);
            float z2 = xb.x * si + 0.5f * (s2 - zb.x * si);
            float z3 = xb.y * si + 0.5f * (s3 - zb.y * si);
            float rs = rsums[node];
            uint2 o; o.x = f2_to_h2(z0 * rs, z1 * rs); o.y = f2_to_h2(z2 * rs, z3 * rs);
            hout[idx] = o;
        } else if (pass == 3) {
            uint2 xw = hxb[idx], zw = hin[idx];
            float2 xa = h2_to_f2(xw.x), xb = h2_to_f2(xw.y);
            float2 za = h2_to_f2(zw.x), zb = h2_to_f2(zw.y);
            float z0 = xa.x * si + (s0 - za.x * si);
            float z1 = xa.y * si + (s1 - za.y * si);
            float z2 = xb.x * si + (s2 - zb.x * si);
            float z3 = xb.y * si + (s3 - zb.y * si);
            float rs = rsums[node];
            uint2 o; o.x = f2_to_h2(z0 * rs, z1 * rs); o.y = f2_to_h2(z2 * rs, z3 * rs);
            hout[idx] = o;
        } else {
            uint2 w1 = ha[idx], w2 = hb[idx], w3 = hin[idx];
            float2 z1a = h2_to_f2(w1.x), z1b = h2_to_f2(w1.y);
            float2 z2a = h2_to_f2(w2.x), z2b = h2_to_f2(w2.y);
            float2 z3a = h2_to_f2(w3.x), z3b = h2_to_f2(w3.y);
            int fb2 = node * DCH + c * 4;
            float x0 = __builtin_nontemporal_load(&x[fb2]);
            float x1 = __builtin_nontemporal_load(&x[fb2 + 1]);
            float x2 = __builtin_nontemporal_load(&x[fb2 + 2]);
            float x3 = __builtin_nontemporal_load(&x[fb2 + 3]);
            float r0 = (s0 + (2.f * z1a.x + 4.f * z2a.x + z3a.x) * si - 2.f * x0) * (1.0f / 6.0f);
            float r1 = (s1 + (2.f * z1a.y + 4.f * z2a.y + z3a.y) * si - 2.f * x1) * (1.0f / 6.0f);
            float r2 = (s2 + (2.f * z1b.x + 4.f * z2b.x + z3b.x) * si - 2.f * x2) * (1.0f / 6.0f);
            float r3 = (s3 + (2.f * z1b.y + 4.f * z2b.y + z3b.y) * si - 2.f * x3) * (1.0f / 6.0f);
            __builtin_nontemporal_store(r0, &zout[fb2]);
            __builtin_nontemporal_store(r1, &zout[fb2 + 1]);
            __builtin_nontemporal_store(r2, &zout[fb2 + 2]);
            __builtin_nontemporal_store(r3, &zout[fb2 + 3]);
        }
    }
}

extern "C" void kernel_launch(void* const* d_in, const int* in_sizes, int n_in,
                              void* d_out, int out_size, void* d_ws, size_t ws_size,
                              hipStream_t stream) {
    const float* x   = (const float*)d_in[0];
    const float* att = (const float*)d_in[1];
    const int*   ei  = (const int*)d_in[2];
    const int E = in_sizes[1];
    const int N = in_sizes[0] / DCH;     // NOTE: src packed in 16 bits -> requires N <= 65536
    const int* src = ei;
    const int* dst = ei + E;

    const int NB  = (N + BKT - 1) / BKT;   // 391
    const int NBG = NB * GBC;
    const int NK2 = 2 * NBG;
    const int EK = E - (int)((long long)(0.2 * (double)(E - 1))) + 64;

    char* ws = (char*)d_ws;
    size_t off = 0;
    auto alloc = [&](size_t b) { size_t o = off; off += (b + 255) & ~(size_t)255; return o; };
    int*    hist2d = (int*)   (ws + alloc((size_t)GB_HIST * NBINS * 4));
    int*    hist   = (int*)   (ws + alloc((size_t)NBINS * 4));
    int*    csum   = (int*)   (ws + alloc(64 * 4));
    // zero region: ctrl + scan state (one memset)
    size_t zbeg = off;
    Ctrl*   ctrl   = (Ctrl*)  (ws + alloc(256));
    unsigned* sstate = (unsigned*)(ws + alloc(512));
    size_t zlen = off - zbeg;
    uint2*  cand   = (uint2*) (ws + alloc((size_t)CAP * 8));
    int*    cntAll = (int*)   (ws + alloc((size_t)2 * SUBC * NBG * 4));
    int*    off2d  = (int*)   (ws + alloc(((size_t)NK2 + 1) * 4));
    float*  rsums  = (float*) (ws + alloc((size_t)N * 4));
    float*  sinv   = (float*) (ws + alloc((size_t)N * 4));
    int*    rowp   = (int*)   (ws + alloc(((size_t)N + 1) * 4));
    uint2*  ebufD  = (uint2*) (ws + alloc((size_t)EK * 8));
    unsigned* csr32= (unsigned*)(ws + alloc((size_t)EK * 4));
    unsigned* ebufS= (unsigned*)(ws + alloc((size_t)EK * 4));
    __half* hx     = (__half*)(ws + alloc((size_t)N * DCH * 2));
    __half* h1     = (__half*)(ws + alloc((size_t)N * DCH * 2));
    __half* h2     = (__half*)(ws + alloc((size_t)N * DCH * 2));
    __half* h3     = (__half*)(ws + alloc((size_t)N * DCH * 2));
    float*  out    = (float*)d_out;

    hipMemsetAsync(ws + zbeg, 0, zlen, stream);

    // numpy-style quantile index arithmetic (float64)
    double q   = 1.0 - 0.8;
    double pos = q * (double)(E - 1);
    long long i0 = (long long)floor(pos);
    double frac  = pos - (double)i0;
    long long i1 = i0 + 1;
    if (i1 > (long long)E - 1) i1 = (long long)E - 1;

    const int nbscan = (NK2 + SCAN_CH - 1) / SCAN_CH;   // 98 blocks, all co-resident

    k_hist    <<<GB_HIST, 512, 0, stream>>>(att, E, hist2d);
    k_fold    <<<NBINS / 64, 256, 0, stream>>>(hist2d, hist, csum);
    k_pick    <<<1, 256, 0, stream>>>(hist, csum, ctrl, i0, i1);
    k_countc  <<<GBC * SUBC, 256, 0, stream>>>(att, src, dst, E, NB, NBG, ctrl,
                                               cntAll, cand);
    k_finalize<<<1, 256, 0, stream>>>(ctrl, cand, src, dst, i0, i1, frac,
                                      cntAll, NB, NBG);
    k_scanAll <<<nbscan, 256, 0, stream>>>(cntAll, NB, NBG, NK2, off2d, sstate);
    k_scatter <<<GBC, 1024, 0, stream>>>(att, src, dst, E, NB, NBG, ctrl, off2d,
                                         cand, ebufD, ebufS);
    k_sortsum <<<2 * NB, 512, 0, stream>>>(off2d, NBG, ebufS, ebufD, x, rsums, sinv,
                                           hx, csr32, rowp, N, NB);

    dim3 blk(64, 4);
    int nb = (N + 3) / 4;
    uint2* hxu = (uint2*)hx;
    uint2* h1u = (uint2*)h1;
    uint2* h2u = (uint2*)h2;
    uint2* h3u = (uint2*)h3;
    k_spmv<<<nb, blk, 0, stream>>>(rowp, csr32, hxu, h1u, hxu, nullptr, nullptr, rsums, sinv, x, nullptr, N, 1);
    k_spmv<<<nb, blk, 0, stream>>>(rowp, csr32, h1u, h2u, hxu, nullptr, nullptr, rsums, sinv, x, nullptr, N, 2);
    k_spmv<<<nb, blk, 0, stream>>>(rowp, csr32, h2u, h3u, hxu, nullptr, nullptr, rsums, sinv, x, nullptr, N, 3);
    k_spmv<<<nb, blk, 0, stream>>>(rowp, csr32, h3u, nullptr, hxu, h1u, h2u, rsums, sinv, x, out, N, 4);
}